// Round 9
// baseline (1016.961 us; speedup 1.0000x reference)
//
#include <hip/hip_runtime.h>
#include <hip/hip_bf16.h>
#include <math.h>

using bf16 = __hip_bfloat16;
#define DI __device__ __forceinline__

namespace {
constexpr int B = 8, C = 48, H = 128, W = 128;
constexpr int HW = H * W;                 // 16384
constexpr int NCHW = B * C * HW;          // 6,291,456
constexpr int C2 = 96;
constexpr int WF = 65;                    // rfft width
constexpr int SPECHW = H * WF;            // 8320 (divisible by 64)
constexpr int SPECN = B * C2 * SPECHW;    // 6,389,760 floats
// spec (fp32) overlays the T+Q+K bf16 region = 3*NCHW bf16 slots
static_assert((size_t)SPECN * 4 <= (size_t)3 * NCHW * 2, "spec must fit in T+Q+K overlay");
static_assert(SPECHW % 64 == 0, "freq_gate 64-pixel blocks must not straddle batches");

// fp32 param header offsets (in floats), base = ws + 8192
constexpr int O_FDW = 0,    O_BNG = 3456, O_BNB = 3528, O_BNM = 3600, O_BNV = 3672;
constexpr int O_FHW1 = 3744, O_FHB1 = 3888, O_FHW2 = 3936, O_FHB2 = 3984;
constexpr int O_FLW = 4032,  O_FLB = 13248;
constexpr int O_HQW = 13344, O_HKVW = 15648, O_HQDW = 20256, O_HKVDW = 20688, O_HPW = 21552, O_HT = 23856;
constexpr int O_LQW = 23860, O_LKVW = 26164, O_LQDW = 30772, O_LKVDW = 31204, O_LPW = 32068, O_LT = 34372;
constexpr int O_FPW = 34376, O_FPB = 38984;  // end 39032

constexpr int NCHUNK = 64;                // L split for attn gram
}

DI float ldf(const float* p, int i) { return p[i]; }
DI float ldf(const bf16* p, int i) { return __bfloat162float(p[i]); }
DI bf16 tob(float x) { return __float2bfloat16(x); }
DI float ldx(const void* p, int i, int bf) {
  return bf ? __bfloat162float(((const bf16*)p)[i]) : ((const float*)p)[i];
}
DI float geluf(float x) { return 0.5f * x * (1.f + erff(x * 0.70710678118654752f)); }
DI int refl(int i, int n) { return i < 0 ? -i : (i >= n ? 2 * n - 2 - i : i); }

// ---- dtype detector: bf16 data -> even u16 slots have sane exponents ----
__global__ void detect_k(const void* x, int* flagp) {
  const unsigned short* u = (const unsigned short*)x;
  int t = threadIdx.x;
  int good = 0;
  for (int i = t; i < 1024; i += 256) {
    unsigned short v = u[2 * i];
    int e = (v >> 7) & 0xFF;
    if (e >= 100 && e <= 140) good++;
  }
  __shared__ int cnt;
  if (t == 0) cnt = 0;
  __syncthreads();
  atomicAdd(&cnt, good);
  __syncthreads();
  if (t == 0) flagp[0] = (cnt > 512) ? 1 : 0;
}

// ---- convert all params to fp32 header ----
struct ParamTab { const void* src[25]; int off[25]; int cnt[25]; };
__global__ void cvt_params_k(ParamTab tab, const int* flagp, float* dst) {
  int bf = flagp[0];
  int b = blockIdx.x;
  const void* s = tab.src[b];
  float* d = dst + tab.off[b];
  int n = tab.cnt[b];
  for (int i = threadIdx.x; i < n; i += 256) d[i] = ldx(s, i, bf);
}

// ---- fd: channel means ----
__global__ void reduce_mean_k(const void* __restrict__ x, float* __restrict__ ap,
                              const int* flagp) {
  int bf = flagp[0];
  int bc = blockIdx.x;
  int base = bc * HW;
  float s = 0.f;
  for (int i = threadIdx.x; i < HW; i += 256) s += ldx(x, base + i, bf);
  #pragma unroll
  for (int o = 32; o > 0; o >>= 1) s += __shfl_down(s, o);
  __shared__ float r[4];
  if ((threadIdx.x & 63) == 0) r[threadIdx.x >> 6] = s;
  __syncthreads();
  if (threadIdx.x == 0) ap[bc] = (r[0] + r[1] + r[2] + r[3]) * (1.f / HW);
}

// ---- fd: 72-wide linear + BN + per-group softmax over 9 ----
__global__ void fd_weights_k(const float* __restrict__ ap, const float* __restrict__ P,
                             float* __restrict__ wts) {
  int n = blockIdx.x, t = threadIdx.x;
  __shared__ float vals[72], es[72];
  if (t < 72) {
    float acc = 0.f;
    for (int c = 0; c < C; c++) acc += P[O_FDW + t * C + c] * ap[n * C + c];
    acc = (acc - P[O_BNM + t]) * rsqrtf(P[O_BNV + t] + 1e-5f);
    vals[t] = acc * P[O_BNG + t] + P[O_BNB + t];
  }
  __syncthreads();
  if (t < 72) {
    int base = (t / 9) * 9;
    float mx = -1e30f;
    for (int k = 0; k < 9; k++) mx = fmaxf(mx, vals[base + k]);
    es[t] = expf(vals[t] - mx);
  }
  __syncthreads();
  if (t < 72) {
    int base = (t / 9) * 9;
    float s = 0.f;
    for (int k = 0; k < 9; k++) s += es[base + k];
    wts[n * 72 + t] = es[t] / s;
  }
}

// ---- fd: involution low-pass (reflect pad), low + high ----
__global__ void fd_apply_k(const void* __restrict__ x, const float* __restrict__ wts,
                           bf16* __restrict__ low, bf16* __restrict__ high,
                           const int* flagp) {
  int bf = flagp[0];
  int idx = blockIdx.x * 256 + threadIdx.x;
  int w = idx & (W - 1);
  int h = (idx >> 7) & (H - 1);
  int c = (idx / HW) % C;
  int b = idx / (C * HW);
  const float* wt = wts + b * 72 + (c / 6) * 9;
  int xbase = (b * C + c) * HW;
  float acc = 0.f, ctr = 0.f;
  #pragma unroll
  for (int i = 0; i < 3; i++) {
    int hh = refl(h + i - 1, H);
    #pragma unroll
    for (int j = 0; j < 3; j++) {
      int ww = refl(w + j - 1, W);
      float v = ldx(x, xbase + hh * W + ww, bf);
      if (i == 1 && j == 1) ctr = v;
      acc += wt[i * 3 + j] * v;
    }
  }
  low[idx] = tob(acc);
  high[idx] = tob(ctr - acc);
}

// ---- fmgm_high: fused (1x3)->(3x1) dwconv (zero pad, biases) -> gelu * x ----
__global__ void fmgm_high_k(const bf16* __restrict__ hi, const float* __restrict__ P,
                            bf16* __restrict__ out) {
  int idx = blockIdx.x * 256 + threadIdx.x;
  int w = idx & (W - 1);
  int h = (idx >> 7) & (H - 1);
  int c = (idx / HW) % C;
  const bf16* p = hi + (idx - (h * W + w));
  float k1[3], k2[3];
  #pragma unroll
  for (int j = 0; j < 3; j++) { k1[j] = P[O_FHW1 + c * 3 + j]; k2[j] = P[O_FHW2 + c * 3 + j]; }
  float bb1 = P[O_FHB1 + c];
  float acc = P[O_FHB2 + c];
  #pragma unroll
  for (int i = 0; i < 3; i++) {
    int hh = h + i - 1;
    if (hh < 0 || hh >= H) continue;
    float y1 = bb1;
    #pragma unroll
    for (int j = 0; j < 3; j++) {
      int ww = w + j - 1;
      if (ww >= 0 && ww < W) y1 += k1[j] * ldf(p, hh * W + ww);
    }
    acc += k2[i] * y1;
  }
  out[idx] = tob(geluf(acc) * ldf(p, h * W + w));
}

// ---- rfft along W, v2: trig recurrence, 4 rows/block, 1 wave/row ----
__global__ void __launch_bounds__(256) rfft_row_k(const bf16* __restrict__ low,
                                                  float* __restrict__ spec) {
  int t = threadIdx.x;
  int wid = t >> 6, l = t & 63;
  int row = blockIdx.x * 4 + wid;        // in [0, B*C*H)
  int h = row & (H - 1);
  int bc = row >> 7;
  int c = bc % C, b = bc / C;
  __shared__ float2 xs[4][64];
  const unsigned* xr = (const unsigned*)(low + (size_t)row * W);
  unsigned v2 = xr[l];                   // two bf16: elems 2l, 2l+1
  xs[wid][l] = make_float2(__uint_as_float(v2 << 16),
                           __uint_as_float(v2 & 0xFFFF0000u));
  __syncthreads();
  float a = (float)l * (1.f / 64.f);
  float ca = cospif(a), sa = sinpif(a);
  float cr = 1.f, ci = 0.f;
  float re = 0.f, im = 0.f, se = 0.f, so = 0.f;
  #pragma unroll 8
  for (int i = 0; i < 64; i++) {
    float2 v = xs[wid][i];
    re += v.x * cr; im -= v.x * ci;      // n = 2i
    se += v.x; so += v.y;
    float t1 = cr * ca - ci * sa; ci = cr * sa + ci * ca; cr = t1;  // -> n=2i+1
    re += v.y * cr; im -= v.y * ci;
    t1 = cr * ca - ci * sa; ci = cr * sa + ci * ca; cr = t1;        // -> n=2i+2
  }
  size_t o = ((size_t)(b * C2 + c) * H + h) * WF + l;
  size_t ioff = (size_t)C * H * WF;
  spec[o] = re;
  spec[o + ioff] = im;
  if (l == 0) {                          // k = 64 (Nyquist): im exactly 0
    spec[o + 64] = se - so;
    spec[o + 64 + ioff] = 0.f;
  }
}

// ---- complex DFT along H, v3: per-(b,c) tile, coalesced, 8-wide k0 batches ----
// waves 0-3: lanes = kx (0..63), 16 k0 each via E/O parity; wave 4: kx=64 column.
// Two LDS parity phases (even rows then odd rows), 32 KB tile.
__global__ void __launch_bounds__(320) fft_col_k(float* __restrict__ spec,
                                                 float sgn, float scale) {
  __shared__ float2 tile[64 * 64];       // 32 KB: one parity of rows x kx 0..63
  int t = threadIdx.x;
  int bc = blockIdx.x;
  int c = bc % C, b = bc / C;
  size_t reb = ((size_t)(b * C2 + c) * H) * WF;
  size_t imb = reb + (size_t)C * H * WF;
  int w = t >> 6, l = t & 63;
  float reE[16], imE[16];
  // ---- phase E: even rows ----
  for (int i = 0; i < 13; i++) {
    int idx = i * 320 + t;
    if (idx < 4096) {
      int r = (idx >> 6) * 2, kx = idx & 63;
      tile[idx] = make_float2(spec[reb + r * WF + kx], spec[imb + r * WF + kx]);
    }
  }
  __syncthreads();
  if (w < 4) {
    for (int jp = 0; jp < 2; jp++) {
      int k0b = w * 16 + jp * 8;
      float cr[8], ci[8], ca[8], sa[8], ar[8], ai[8];
      #pragma unroll
      for (int j = 0; j < 8; j++) {
        float a = (float)(k0b + j) * (1.f / 32.f);   // step over n+=2
        ca[j] = cospif(a); sa[j] = sinpif(a) * sgn;
        cr[j] = 1.f; ci[j] = 0.f; ar[j] = 0.f; ai[j] = 0.f;
      }
      for (int i = 0; i < 64; i++) {
        float2 v = tile[i * 64 + l];
        #pragma unroll
        for (int j = 0; j < 8; j++) {
          ar[j] += v.x * cr[j] - v.y * ci[j];
          ai[j] += v.y * cr[j] + v.x * ci[j];
          float t1 = cr[j] * ca[j] - ci[j] * sa[j];
          ci[j] = cr[j] * sa[j] + ci[j] * ca[j]; cr[j] = t1;
        }
      }
      #pragma unroll
      for (int j = 0; j < 8; j++) { reE[jp * 8 + j] = ar[j]; imE[jp * 8 + j] = ai[j]; }
    }
  }
  __syncthreads();
  // ---- phase O: odd rows ----
  for (int i = 0; i < 13; i++) {
    int idx = i * 320 + t;
    if (idx < 4096) {
      int r = (idx >> 6) * 2 + 1, kx = idx & 63;
      tile[idx] = make_float2(spec[reb + r * WF + kx], spec[imb + r * WF + kx]);
    }
  }
  __syncthreads();
  if (w < 4) {
    for (int jp = 0; jp < 2; jp++) {
      int k0b = w * 16 + jp * 8;
      float cr[8], ci[8], ca[8], sa[8], ar[8], ai[8];
      #pragma unroll
      for (int j = 0; j < 8; j++) {
        float a0 = (float)(k0b + j) * (1.f / 64.f);  // tw at n=1
        float a = (float)(k0b + j) * (1.f / 32.f);
        ca[j] = cospif(a); sa[j] = sinpif(a) * sgn;
        cr[j] = cospif(a0); ci[j] = sinpif(a0) * sgn;
        ar[j] = 0.f; ai[j] = 0.f;
      }
      for (int i = 0; i < 64; i++) {
        float2 v = tile[i * 64 + l];
        #pragma unroll
        for (int j = 0; j < 8; j++) {
          ar[j] += v.x * cr[j] - v.y * ci[j];
          ai[j] += v.y * cr[j] + v.x * ci[j];
          float t1 = cr[j] * ca[j] - ci[j] * sa[j];
          ci[j] = cr[j] * sa[j] + ci[j] * ca[j]; cr[j] = t1;
        }
      }
      #pragma unroll
      for (int j = 0; j < 8; j++) {
        int k0 = k0b + j;
        float rE = reE[jp * 8 + j], iE = imE[jp * 8 + j];
        spec[reb + (size_t)k0 * WF + l]        = (rE + ar[j]) * scale;
        spec[imb + (size_t)k0 * WF + l]        = (iE + ai[j]) * scale;
        spec[reb + (size_t)(k0 + 64) * WF + l] = (rE - ar[j]) * scale;
        spec[imb + (size_t)(k0 + 64) * WF + l] = (iE - ai[j]) * scale;
      }
    }
  } else {
    // wave 4: kx = 64 column (lane = k0), reads global directly (disjoint addrs)
    float a = (float)l * (1.f / 64.f);
    float ca = cospif(a), sa = sinpif(a) * sgn;
    float cr = 1.f, ci = 0.f;
    float rE = 0.f, iE = 0.f, rO = 0.f, iO = 0.f;
    for (int n = 0; n < 128; n += 2) {
      float vr = spec[reb + (size_t)n * WF + 64];
      float vi = spec[imb + (size_t)n * WF + 64];
      rE += vr * cr - vi * ci; iE += vi * cr + vr * ci;
      float t1 = cr * ca - ci * sa; ci = cr * sa + ci * ca; cr = t1;
      vr = spec[reb + (size_t)(n + 1) * WF + 64];
      vi = spec[imb + (size_t)(n + 1) * WF + 64];
      rO += vr * cr - vi * ci; iO += vi * cr + vr * ci;
      t1 = cr * ca - ci * sa; ci = cr * sa + ci * ca; cr = t1;
    }
    spec[reb + (size_t)l * WF + 64]        = (rE + rO) * scale;
    spec[imb + (size_t)l * WF + 64]        = (iE + iO) * scale;
    spec[reb + (size_t)(l + 64) * WF + 64] = (rE - rO) * scale;
    spec[imb + (size_t)(l + 64) * WF + 64] = (iE - iO) * scale;
  }
}

// ---- freq-domain channel-mix gate: yf *= gelu(W yf + b) ----
__global__ void __launch_bounds__(256) freq_gate_k(float* __restrict__ spec,
                                                   const float* __restrict__ P) {
  __shared__ float vs[96 * 65];
  int t = threadIdx.x;
  int blk = blockIdx.x;
  int b = blk / (SPECHW / 64);
  int pp0 = (blk % (SPECHW / 64)) * 64;
  float* sb = spec + (size_t)b * C2 * SPECHW + pp0;
  #pragma unroll
  for (int i = 0; i < 24; i++) {
    int idx = i * 256 + t;
    int c = idx >> 6, p = idx & 63;
    vs[c * 65 + p] = sb[(size_t)c * SPECHW + p];
  }
  __syncthreads();
  int p = t & 63;
  int og = __builtin_amdgcn_readfirstlane(t >> 6);   // wave-uniform 0..3
  const float* Wrow = P + O_FLW + og * 24 * 96;      // uniform base -> s_loads
  float acc[24];
  #pragma unroll
  for (int j = 0; j < 24; j++) acc[j] = 0.f;
  for (int c = 0; c < 96; c++) {
    float vv = vs[c * 65 + p];
    #pragma unroll
    for (int j = 0; j < 24; j++) acc[j] += Wrow[j * 96 + c] * vv;
  }
  #pragma unroll
  for (int j = 0; j < 24; j++) {
    int o = og * 24 + j;
    float g = geluf(acc[j] + P[O_FLB + o]);
    sb[(size_t)o * SPECHW + p] = vs[o * 65 + p] * g;
  }
}

// ---- irfft along W, v2: recurrence + even/odd-k parity ----
__global__ void __launch_bounds__(256) irfft_row_k(const float* __restrict__ spec,
                                                   bf16* __restrict__ out) {
  int t = threadIdx.x;
  int wid = t >> 6, l = t & 63;
  int row = blockIdx.x * 4 + wid;        // in [0, B*C*H)
  int h = row & (H - 1);
  int bc = row >> 7;
  int c = bc % C, b = bc / C;
  __shared__ float2 rim[4][64];
  __shared__ float r64[4];
  size_t rb = ((size_t)(b * C2 + c) * H + h) * WF;
  size_t ioff = (size_t)C * H * WF;
  rim[wid][l] = make_float2(spec[rb + l], spec[rb + ioff + l]);
  if (l == 0) r64[wid] = spec[rb + 64];
  __syncthreads();
  float re0 = rim[wid][0].x;
  float re64 = r64[wid];
  float a = (float)l * (1.f / 64.f);
  float ca = cospif(a), sa = sinpif(a);
  float cr = ca, ci = sa;                // rotation at k=1
  float accE = 0.f, accO = 0.f;          // even-k / odd-k partials (k>=1)
  #pragma unroll 8
  for (int k = 1; k <= 61; k += 2) {
    float2 v = rim[wid][k];
    accO += v.x * cr - v.y * ci;
    float t1 = cr * ca - ci * sa; ci = cr * sa + ci * ca; cr = t1;   // -> k+1
    v = rim[wid][k + 1];
    accE += v.x * cr - v.y * ci;
    t1 = cr * ca - ci * sa; ci = cr * sa + ci * ca; cr = t1;         // -> k+2
  }
  { // k = 63 epilogue (odd)
    float2 v = rim[wid][63];
    accO += v.x * cr - v.y * ci;
  }
  float base = re0 + ((l & 1) ? -re64 : re64);
  float x0 = (base + 2.f * (accE + accO)) * (1.f / 128.f);
  float x1 = (base + 2.f * (accE - accO)) * (1.f / 128.f);
  bf16* ob = out + (size_t)row * W;
  ob[l] = tob(x0);
  ob[l + 64] = tob(x1);
}

// ---- 1x1 conv v2: 64 px/block, 4 waves x 12 outputs, s_load weights ----
// mode 1: input is the external x (flag-dtyped); mode 0: internal bf16
__global__ void __launch_bounds__(256) conv1x1_k(const void* __restrict__ in, bf16* __restrict__ out,
                                                 const float* __restrict__ w,
                                                 const int* flagp, int mode) {
  int bf = mode ? flagp[0] : 1;
  __shared__ float vs[48 * 64];
  int t = threadIdx.x;
  int blk = blockIdx.x;                // B * 256
  int b = blk >> 8;
  int p0 = (blk & 255) << 6;
  int ibase = b * 48 * HW + p0;
  #pragma unroll
  for (int i = 0; i < 12; i++) {
    int idx = i * 256 + t;
    int c = idx >> 6, p = idx & 63;
    vs[idx] = ldx(in, ibase + c * HW + p, bf);
  }
  __syncthreads();
  int p = t & 63;
  int og = __builtin_amdgcn_readfirstlane(t >> 6);   // wave-uniform 0..3
  const float* Wrow = w + og * 12 * 48;              // uniform -> s_loads
  float acc[12];
  #pragma unroll
  for (int j = 0; j < 12; j++) acc[j] = 0.f;
  for (int c = 0; c < 48; c++) {
    float v = vs[c * 64 + p];
    #pragma unroll
    for (int j = 0; j < 12; j++) acc[j] += Wrow[j * 48 + c] * v;
  }
  bf16* op = out + (size_t)b * 48 * HW + p0 + p;
  #pragma unroll
  for (int j = 0; j < 12; j++) op[(size_t)(og * 12 + j) * HW] = tob(acc[j]);
}

// ---- depthwise 3x3 (48ch), zero pad, no bias; w pre-offset fp32 ----
__global__ void dw3x3_k(const bf16* __restrict__ in, bf16* __restrict__ out,
                        const float* __restrict__ w) {
  int idx = blockIdx.x * 256 + threadIdx.x;
  int ww = idx & (W - 1);
  int h = (idx >> 7) & (H - 1);
  int c = (idx / HW) % 48;
  const bf16* p = in + (size_t)(idx / HW) * HW;
  float acc = 0.f;
  #pragma unroll
  for (int i = 0; i < 3; i++) {
    int hh = h + i - 1;
    if (hh < 0 || hh >= H) continue;
    #pragma unroll
    for (int j = 0; j < 3; j++) {
      int wj = ww + j - 1;
      if (wj < 0 || wj >= W) continue;
      acc += w[c * 9 + i * 3 + j] * ldf(p, hh * W + wj);
    }
  }
  out[idx] = tob(acc);
}

// ---- attn gram, split-L partials: grid = 32 bh * NCHUNK blocks ----
__global__ void __launch_bounds__(256) attn_part_k(const bf16* __restrict__ q,
                                                   const bf16* __restrict__ kbuf,
                                                   float* __restrict__ partial) {
  int blk = blockIdx.x;
  int bh = blk >> 6, chunk = blk & (NCHUNK - 1);
  int b = bh >> 2, hd = bh & 3;
  int t = threadIdx.x;
  int l0 = chunk * 256;
  __shared__ float qs[12 * 257], ks[12 * 257];
  const bf16* qb = q + (size_t)(b * 48 + hd * 12) * HW + l0;
  const bf16* kb = kbuf + (size_t)(b * 48 + hd * 12) * HW + l0;
  #pragma unroll
  for (int m = 0; m < 12; m++) {
    qs[m * 257 + t] = ldf(qb, m * HW + t);
    ks[m * 257 + t] = ldf(kb, m * HW + t);
  }
  __syncthreads();
  float acc = 0.f;
  if (t < 144) {
    const float* qr = qs + (t / 12) * 257;
    const float* kr = ks + (t % 12) * 257;
    #pragma unroll 4
    for (int j = 0; j < 256; j++) acc += qr[j] * kr[j];
  } else if (t < 156) {
    const float* qr = qs + (t - 144) * 257;
    #pragma unroll 4
    for (int j = 0; j < 256; j++) acc += qr[j] * qr[j];
  } else if (t < 168) {
    const float* kr = ks + (t - 156) * 257;
    #pragma unroll 4
    for (int j = 0; j < 256; j++) acc += kr[j] * kr[j];
  }
  if (t < 168) partial[(size_t)(chunk * 32 + bh) * 168 + t] = acc;
}

// ---- reduce partials + norms + softmax -> 12x12 attn per bh ----
__global__ void __launch_bounds__(256) attn_fin_k(const float* __restrict__ partial,
                                                  const float* __restrict__ temp,
                                                  float* __restrict__ attn) {
  int bh = blockIdx.x, hd = bh & 3;
  int t = threadIdx.x;
  __shared__ float red[168];
  if (t < 168) {
    float s = 0.f;
    for (int ch = 0; ch < NCHUNK; ch++) s += partial[(size_t)(ch * 32 + bh) * 168 + t];
    red[t] = s;
  }
  __syncthreads();
  if (t < 12) {
    float tm = temp[hd];
    float rq = 1.f / fmaxf(sqrtf(red[144 + t]), 1e-12f);
    float vals[12], mx = -1e30f;
    #pragma unroll
    for (int d = 0; d < 12; d++) {
      float rk = 1.f / fmaxf(sqrtf(red[156 + d]), 1e-12f);
      vals[d] = red[t * 12 + d] * rq * rk * tm;
      mx = fmaxf(mx, vals[d]);
    }
    float s = 0.f;
    #pragma unroll
    for (int d = 0; d < 12; d++) { vals[d] = expf(vals[d] - mx); s += vals[d]; }
    float inv = 1.f / s;
    float* ao = attn + (size_t)(bh * 12 + t) * 12;
    #pragma unroll
    for (int d = 0; d < 12; d++) ao[d] = vals[d] * inv;
  }
}

// ---- out = attn @ v ----
__global__ void attn_apply_k(const float* __restrict__ attn, const bf16* __restrict__ vbuf,
                             bf16* __restrict__ out) {
  int blk = blockIdx.x;
  int bh = blk >> 6, b = bh >> 2, hd = bh & 3;
  int l = ((blk & 63) << 8) + threadIdx.x;
  __shared__ float al[144];
  if (threadIdx.x < 144) al[threadIdx.x] = attn[bh * 144 + threadIdx.x];
  __syncthreads();
  const bf16* vb = vbuf + (size_t)(b * 48 + hd * 12) * HW + l;
  float vv[12];
  #pragma unroll
  for (int d = 0; d < 12; d++) vv[d] = ldf(vb, d * HW);
  bf16* ob = out + (size_t)(b * 48 + hd * 12) * HW + l;
  #pragma unroll
  for (int c = 0; c < 12; c++) {
    float s = 0.f;
    #pragma unroll
    for (int d = 0; d < 12; d++) s += al[c * 12 + d] * vv[d];
    ob[(size_t)c * HW] = tob(s);
  }
}

// ---- final v2: 64 px/block, 4 waves x 12 outputs, s_load weights ----
__global__ void __launch_bounds__(256) conv_final_k(const bf16* __restrict__ ho,
                                                    const bf16* __restrict__ lo,
                                                    const float* __restrict__ P,
                                                    const void* __restrict__ x,
                                                    void* __restrict__ out,
                                                    const int* flagp) {
  int bf = flagp[0];
  __shared__ float vs[96 * 64];
  int t = threadIdx.x;
  int blk = blockIdx.x;                // B * 256
  int b = blk >> 8;
  int p0 = (blk & 255) << 6;
  int pbase = b * 48 * HW + p0;
  #pragma unroll
  for (int i = 0; i < 12; i++) {
    int idx = i * 256 + t;
    int c = idx >> 6, p = idx & 63;
    vs[idx] = ldf(ho, pbase + c * HW + p);
    vs[48 * 64 + idx] = ldf(lo, pbase + c * HW + p);
  }
  __syncthreads();
  int p = t & 63;
  int og = __builtin_amdgcn_readfirstlane(t >> 6);   // wave-uniform 0..3
  const float* Wrow = P + O_FPW + og * 12 * 96;      // uniform -> s_loads
  float acc[12];
  #pragma unroll
  for (int j = 0; j < 12; j++) acc[j] = 0.f;
  for (int c = 0; c < 96; c++) {
    float v = vs[c * 64 + p];
    #pragma unroll
    for (int j = 0; j < 12; j++) acc[j] += Wrow[j * 96 + c] * v;
  }
  #pragma unroll
  for (int j = 0; j < 12; j++) {
    int o = og * 12 + j;
    int oi = pbase + o * HW + p;
    float val = acc[j] + P[O_FPB + o] + ldx(x, oi, bf);
    if (bf) ((bf16*)out)[oi] = tob(val);
    else    ((float*)out)[oi] = val;
  }
}

extern "C" void kernel_launch(void* const* d_in, const int* in_sizes, int n_in,
                              void* d_out, int out_size, void* d_ws, size_t ws_size,
                              hipStream_t stream) {
  const void* x = d_in[0];

  // ws layout (fp32 units): ap@0, wts@512, attnm@2048, flag@7000,
  // params@8192 (ends 47224), partials@49152 (64*32*168 -> ends 393216),
  // bf16 planes @400000
  float* ws    = (float*)d_ws;
  float* ap    = ws;
  float* wts   = ws + 512;
  float* attnm = ws + 2048;
  int*   flagp = (int*)(ws + 7000);
  float* P     = ws + 8192;
  float* parts = ws + 49152;
  bf16* base = (bf16*)(ws + 400000);
  bf16* HF = base;
  bf16* LF = base + (size_t)NCHW;
  bf16* T  = base + (size_t)2 * NCHW;
  bf16* Q  = base + (size_t)3 * NCHW;
  bf16* K  = base + (size_t)4 * NCHW;
  float* spec = (float*)T;

  // ---- dtype detect + param convert ----
  detect_k<<<1, 256, 0, stream>>>(x, flagp);
  ParamTab tab;
  const int offs[25] = {O_FDW, O_BNG, O_BNB, O_BNM, O_BNV,
                        O_FHW1, O_FHB1, O_FHW2, O_FHB2,
                        O_FLW, O_FLB,
                        O_HQW, O_HKVW, O_HQDW, O_HKVDW, O_HPW, O_HT,
                        O_LQW, O_LKVW, O_LQDW, O_LKVDW, O_LPW, O_LT,
                        O_FPW, O_FPB};
  const int cnts[25] = {3456, 72, 72, 72, 72,
                        144, 48, 144, 48,
                        9216, 96,
                        2304, 4608, 432, 864, 2304, 4,
                        2304, 4608, 432, 864, 2304, 4,
                        4608, 48};
  for (int i = 0; i < 25; i++) { tab.src[i] = d_in[i + 1]; tab.off[i] = offs[i]; tab.cnt[i] = cnts[i]; }
  cvt_params_k<<<25, 256, 0, stream>>>(tab, flagp, P);

  // ---- fd ----
  reduce_mean_k<<<B * C, 256, 0, stream>>>(x, ap, flagp);
  fd_weights_k<<<B, 128, 0, stream>>>(ap, P, wts);
  fd_apply_k<<<NCHW / 256, 256, 0, stream>>>(x, wts, LF, Q, flagp);   // low->LF, high->Q
  // ---- fmgm_high ----
  fmgm_high_k<<<NCHW / 256, 256, 0, stream>>>(Q, P, HF);              // hf->HF
  // ---- fmgm_low: rfft2 -> gate -> irfft2 ----
  rfft_row_k<<<B * C * H / 4, 256, 0, stream>>>(LF, spec);
  fft_col_k<<<B * C, 320, 0, stream>>>(spec, -1.f, 1.f);
  freq_gate_k<<<B * (SPECHW / 64), 256, 0, stream>>>(spec, P);
  fft_col_k<<<B * C, 320, 0, stream>>>(spec, 1.f, 1.f / 128.f);
  irfft_row_k<<<B * C * H / 4, 256, 0, stream>>>(spec, LF);           // lf->LF
  // ---- fga (high branch: freq = hf in HF) ----
  conv1x1_k<<<B * 256, 256, 0, stream>>>(HF, T, P + O_HQW, flagp, 0);
  dw3x3_k<<<NCHW / 256, 256, 0, stream>>>(T, Q, P + O_HQDW);          // q->Q (high dead)
  conv1x1_k<<<B * 256, 256, 0, stream>>>(x, T, P + O_HKVW, flagp, 1);
  dw3x3_k<<<NCHW / 256, 256, 0, stream>>>(T, K, P + O_HKVDW);         // k->K
  conv1x1_k<<<B * 256, 256, 0, stream>>>(x, T, P + O_HKVW + 48 * 48, flagp, 1);
  dw3x3_k<<<NCHW / 256, 256, 0, stream>>>(T, HF, P + O_HKVDW + 48 * 9); // v->HF (hf dead)
  attn_part_k<<<32 * NCHUNK, 256, 0, stream>>>(Q, K, parts);
  attn_fin_k<<<32, 256, 0, stream>>>(parts, P + O_HT, attnm);
  attn_apply_k<<<B * 4 * 64, 256, 0, stream>>>(attnm, HF, K);         // attnout->K (k dead)
  conv1x1_k<<<B * 256, 256, 0, stream>>>(K, Q, P + O_HPW, flagp, 0);  // ho->Q (q dead)
  // ---- fga (low branch: freq = lf in LF) ----
  conv1x1_k<<<B * 256, 256, 0, stream>>>(LF, T, P + O_LQW, flagp, 0);
  dw3x3_k<<<NCHW / 256, 256, 0, stream>>>(T, HF, P + O_LQDW);         // q->HF
  conv1x1_k<<<B * 256, 256, 0, stream>>>(x, T, P + O_LKVW, flagp, 1);
  dw3x3_k<<<NCHW / 256, 256, 0, stream>>>(T, K, P + O_LKVDW);         // k->K
  conv1x1_k<<<B * 256, 256, 0, stream>>>(x, T, P + O_LKVW + 48 * 48, flagp, 1);
  dw3x3_k<<<NCHW / 256, 256, 0, stream>>>(T, LF, P + O_LKVDW + 48 * 9); // v->LF (lf dead)
  attn_part_k<<<32 * NCHUNK, 256, 0, stream>>>(HF, K, parts);
  attn_fin_k<<<32, 256, 0, stream>>>(parts, P + O_LT, attnm);
  attn_apply_k<<<B * 4 * 64, 256, 0, stream>>>(attnm, LF, K);         // attnout->K
  conv1x1_k<<<B * 256, 256, 0, stream>>>(K, T, P + O_LPW, flagp, 0);  // lo->T
  // ---- final 1x1 + bias + residual ----
  conv_final_k<<<B * 256, 256, 0, stream>>>(Q, T, P, x, d_out, flagp);
}

// Round 10
// 906.362 us; speedup vs baseline: 1.1220x; 1.1220x over previous
//
#include <hip/hip_runtime.h>
#include <hip/hip_bf16.h>
#include <math.h>

using bf16 = __hip_bfloat16;
#define DI __device__ __forceinline__

namespace {
constexpr int B = 8, C = 48, H = 128, W = 128;
constexpr int HW = H * W;                 // 16384
constexpr int NCHW = B * C * HW;          // 6,291,456
constexpr int C2 = 96;
constexpr int WF = 65;                    // rfft width
constexpr int SPECHW = H * WF;            // 8320 (divisible by 64)
constexpr int SPECN = B * C2 * SPECHW;    // 6,389,760 floats
// spec (fp32) overlays the T+Q+K bf16 region = 3*NCHW bf16 slots
static_assert((size_t)SPECN * 4 <= (size_t)3 * NCHW * 2, "spec must fit in T+Q+K overlay");
static_assert(SPECHW % 64 == 0, "freq_gate 64-pixel blocks must not straddle batches");

// fp32 param header offsets (in floats), base = ws + 8192
constexpr int O_FDW = 0,    O_BNG = 3456, O_BNB = 3528, O_BNM = 3600, O_BNV = 3672;
constexpr int O_FHW1 = 3744, O_FHB1 = 3888, O_FHW2 = 3936, O_FHB2 = 3984;
constexpr int O_FLW = 4032,  O_FLB = 13248;
constexpr int O_HQW = 13344, O_HKVW = 15648, O_HQDW = 20256, O_HKVDW = 20688, O_HPW = 21552, O_HT = 23856;
constexpr int O_LQW = 23860, O_LKVW = 26164, O_LQDW = 30772, O_LKVDW = 31204, O_LPW = 32068, O_LT = 34372;
constexpr int O_FPW = 34376, O_FPB = 38984;  // end 39032

constexpr int NCHUNK = 64;                // L split for attn gram
}

DI float ldf(const float* p, int i) { return p[i]; }
DI float ldf(const bf16* p, int i) { return __bfloat162float(p[i]); }
DI bf16 tob(float x) { return __float2bfloat16(x); }
DI unsigned short b2u(bf16 v) { union { bf16 b; unsigned short u; } x; x.b = v; return x.u; }
DI float u2f(unsigned short u) { return __uint_as_float((unsigned)u << 16); }
DI float ldx(const void* p, int i, int bf) {
  return bf ? __bfloat162float(((const bf16*)p)[i]) : ((const float*)p)[i];
}
DI float geluf(float x) { return 0.5f * x * (1.f + erff(x * 0.70710678118654752f)); }
DI int refl(int i, int n) { return i < 0 ? -i : (i >= n ? 2 * n - 2 - i : i); }

// ---- dtype detector: bf16 data -> even u16 slots have sane exponents ----
__global__ void detect_k(const void* x, int* flagp) {
  const unsigned short* u = (const unsigned short*)x;
  int t = threadIdx.x;
  int good = 0;
  for (int i = t; i < 1024; i += 256) {
    unsigned short v = u[2 * i];
    int e = (v >> 7) & 0xFF;
    if (e >= 100 && e <= 140) good++;
  }
  __shared__ int cnt;
  if (t == 0) cnt = 0;
  __syncthreads();
  atomicAdd(&cnt, good);
  __syncthreads();
  if (t == 0) flagp[0] = (cnt > 512) ? 1 : 0;
}

// ---- convert all params to fp32 header ----
struct ParamTab { const void* src[25]; int off[25]; int cnt[25]; };
__global__ void cvt_params_k(ParamTab tab, const int* flagp, float* dst) {
  int bf = flagp[0];
  int b = blockIdx.x;
  const void* s = tab.src[b];
  float* d = dst + tab.off[b];
  int n = tab.cnt[b];
  for (int i = threadIdx.x; i < n; i += 256) d[i] = ldx(s, i, bf);
}

// ---- fd: channel means ----
__global__ void reduce_mean_k(const void* __restrict__ x, float* __restrict__ ap,
                              const int* flagp) {
  int bf = flagp[0];
  int bc = blockIdx.x;
  int base = bc * HW;
  float s = 0.f;
  for (int i = threadIdx.x; i < HW; i += 256) s += ldx(x, base + i, bf);
  #pragma unroll
  for (int o = 32; o > 0; o >>= 1) s += __shfl_down(s, o);
  __shared__ float r[4];
  if ((threadIdx.x & 63) == 0) r[threadIdx.x >> 6] = s;
  __syncthreads();
  if (threadIdx.x == 0) ap[bc] = (r[0] + r[1] + r[2] + r[3]) * (1.f / HW);
}

// ---- fd: 72-wide linear + BN + per-group softmax over 9 ----
__global__ void fd_weights_k(const float* __restrict__ ap, const float* __restrict__ P,
                             float* __restrict__ wts) {
  int n = blockIdx.x, t = threadIdx.x;
  __shared__ float vals[72], es[72];
  if (t < 72) {
    float acc = 0.f;
    for (int c = 0; c < C; c++) acc += P[O_FDW + t * C + c] * ap[n * C + c];
    acc = (acc - P[O_BNM + t]) * rsqrtf(P[O_BNV + t] + 1e-5f);
    vals[t] = acc * P[O_BNG + t] + P[O_BNB + t];
  }
  __syncthreads();
  if (t < 72) {
    int base = (t / 9) * 9;
    float mx = -1e30f;
    for (int k = 0; k < 9; k++) mx = fmaxf(mx, vals[base + k]);
    es[t] = expf(vals[t] - mx);
  }
  __syncthreads();
  if (t < 72) {
    int base = (t / 9) * 9;
    float s = 0.f;
    for (int k = 0; k < 9; k++) s += es[base + k];
    wts[n * 72 + t] = es[t] / s;
  }
}

// ---- fd: involution low-pass (reflect pad), low + high ----
__global__ void fd_apply_k(const void* __restrict__ x, const float* __restrict__ wts,
                           bf16* __restrict__ low, bf16* __restrict__ high,
                           const int* flagp) {
  int bf = flagp[0];
  int idx = blockIdx.x * 256 + threadIdx.x;
  int w = idx & (W - 1);
  int h = (idx >> 7) & (H - 1);
  int c = (idx / HW) % C;
  int b = idx / (C * HW);
  const float* wt = wts + b * 72 + (c / 6) * 9;
  int xbase = (b * C + c) * HW;
  float acc = 0.f, ctr = 0.f;
  #pragma unroll
  for (int i = 0; i < 3; i++) {
    int hh = refl(h + i - 1, H);
    #pragma unroll
    for (int j = 0; j < 3; j++) {
      int ww = refl(w + j - 1, W);
      float v = ldx(x, xbase + hh * W + ww, bf);
      if (i == 1 && j == 1) ctr = v;
      acc += wt[i * 3 + j] * v;
    }
  }
  low[idx] = tob(acc);
  high[idx] = tob(ctr - acc);
}

// ---- fmgm_high: fused (1x3)->(3x1) dwconv (zero pad, biases) -> gelu * x ----
__global__ void fmgm_high_k(const bf16* __restrict__ hi, const float* __restrict__ P,
                            bf16* __restrict__ out) {
  int idx = blockIdx.x * 256 + threadIdx.x;
  int w = idx & (W - 1);
  int h = (idx >> 7) & (H - 1);
  int c = (idx / HW) % C;
  const bf16* p = hi + (idx - (h * W + w));
  float k1[3], k2[3];
  #pragma unroll
  for (int j = 0; j < 3; j++) { k1[j] = P[O_FHW1 + c * 3 + j]; k2[j] = P[O_FHW2 + c * 3 + j]; }
  float bb1 = P[O_FHB1 + c];
  float acc = P[O_FHB2 + c];
  #pragma unroll
  for (int i = 0; i < 3; i++) {
    int hh = h + i - 1;
    if (hh < 0 || hh >= H) continue;
    float y1 = bb1;
    #pragma unroll
    for (int j = 0; j < 3; j++) {
      int ww = w + j - 1;
      if (ww >= 0 && ww < W) y1 += k1[j] * ldf(p, hh * W + ww);
    }
    acc += k2[i] * y1;
  }
  out[idx] = tob(geluf(acc) * ldf(p, h * W + w));
}

// ---- rfft along W, v2: trig recurrence, 4 rows/block, 1 wave/row ----
__global__ void __launch_bounds__(256) rfft_row_k(const bf16* __restrict__ low,
                                                  float* __restrict__ spec) {
  int t = threadIdx.x;
  int wid = t >> 6, l = t & 63;
  int row = blockIdx.x * 4 + wid;        // in [0, B*C*H)
  int h = row & (H - 1);
  int bc = row >> 7;
  int c = bc % C, b = bc / C;
  __shared__ float2 xs[4][64];
  const unsigned* xr = (const unsigned*)(low + (size_t)row * W);
  unsigned v2 = xr[l];                   // two bf16: elems 2l, 2l+1
  xs[wid][l] = make_float2(__uint_as_float(v2 << 16),
                           __uint_as_float(v2 & 0xFFFF0000u));
  __syncthreads();
  float a = (float)l * (1.f / 64.f);
  float ca = cospif(a), sa = sinpif(a);
  float cr = 1.f, ci = 0.f;
  float re = 0.f, im = 0.f, se = 0.f, so = 0.f;
  #pragma unroll 8
  for (int i = 0; i < 64; i++) {
    float2 v = xs[wid][i];
    re += v.x * cr; im -= v.x * ci;      // n = 2i
    se += v.x; so += v.y;
    float t1 = cr * ca - ci * sa; ci = cr * sa + ci * ca; cr = t1;  // -> n=2i+1
    re += v.y * cr; im -= v.y * ci;
    t1 = cr * ca - ci * sa; ci = cr * sa + ci * ca; cr = t1;        // -> n=2i+2
  }
  size_t o = ((size_t)(b * C2 + c) * H + h) * WF + l;
  size_t ioff = (size_t)C * H * WF;
  spec[o] = re;
  spec[o + ioff] = im;
  if (l == 0) {                          // k = 64 (Nyquist): im exactly 0
    spec[o + 64] = se - so;
    spec[o + 64 + ioff] = 0.f;
  }
}

// ---- complex DFT along H, v4: per-(b,c) tile, 16 waves, 4 k0/wave ----
// tile[64][65] holds one row-parity incl. kx=64; wave 0 also handles kx=64.
__global__ void __launch_bounds__(1024) fft_col_k(float* __restrict__ spec,
                                                  float sgn, float scale) {
  __shared__ float2 tile[64 * 65];       // 33.3 KB
  int t = threadIdx.x;
  int w = t >> 6, l = t & 63;
  int bc = blockIdx.x;
  int c = bc % C, b = bc / C;
  size_t reb = ((size_t)(b * C2 + c) * H) * WF;
  size_t imb = reb + (size_t)C * H * WF;

  float ca[4], sa[4], reE[4], imE[4];
  #pragma unroll
  for (int j = 0; j < 4; j++) {
    float a = (float)(w * 4 + j) * (1.f / 32.f);   // step for n += 2
    ca[j] = cospif(a); sa[j] = sinpif(a) * sgn;
  }
  float a64c = 0.f, a64s = 0.f, rE64 = 0.f, iE64 = 0.f;
  if (w == 0) { float a = (float)l * (1.f / 32.f); a64c = cospif(a); a64s = sinpif(a) * sgn; }

  // ---- phase E: even rows ----
  for (int i = 0; i < 5; i++) {
    int idx = i * 1024 + t;
    if (idx < 4160) {
      int r = (idx / 65) * 2, kx = idx % 65;
      tile[idx] = make_float2(spec[reb + r * WF + kx], spec[imb + r * WF + kx]);
    }
  }
  __syncthreads();
  {
    float cr[4], ci[4], ar[4] = {0,0,0,0}, ai[4] = {0,0,0,0};
    #pragma unroll
    for (int j = 0; j < 4; j++) { cr[j] = 1.f; ci[j] = 0.f; }
    for (int i = 0; i < 64; i++) {
      float2 v = tile[i * 65 + l];
      #pragma unroll
      for (int j = 0; j < 4; j++) {
        ar[j] += v.x * cr[j] - v.y * ci[j];
        ai[j] += v.y * cr[j] + v.x * ci[j];
        float t1 = cr[j] * ca[j] - ci[j] * sa[j];
        ci[j] = cr[j] * sa[j] + ci[j] * ca[j]; cr[j] = t1;
      }
    }
    #pragma unroll
    for (int j = 0; j < 4; j++) { reE[j] = ar[j]; imE[j] = ai[j]; }
    if (w == 0) {                        // kx = 64, lane = k0, broadcast reads
      float crr = 1.f, cii = 0.f;
      for (int i = 0; i < 64; i++) {
        float2 v = tile[i * 65 + 64];
        rE64 += v.x * crr - v.y * cii; iE64 += v.y * crr + v.x * cii;
        float t1 = crr * a64c - cii * a64s; cii = crr * a64s + cii * a64c; crr = t1;
      }
    }
  }
  __syncthreads();
  // ---- phase O: odd rows ----
  for (int i = 0; i < 5; i++) {
    int idx = i * 1024 + t;
    if (idx < 4160) {
      int r = (idx / 65) * 2 + 1, kx = idx % 65;
      tile[idx] = make_float2(spec[reb + r * WF + kx], spec[imb + r * WF + kx]);
    }
  }
  __syncthreads();
  {
    float cr[4], ci[4], ar[4] = {0,0,0,0}, ai[4] = {0,0,0,0};
    #pragma unroll
    for (int j = 0; j < 4; j++) {
      float a0 = (float)(w * 4 + j) * (1.f / 64.f);  // twiddle at n=1
      cr[j] = cospif(a0); ci[j] = sinpif(a0) * sgn;
    }
    for (int i = 0; i < 64; i++) {
      float2 v = tile[i * 65 + l];
      #pragma unroll
      for (int j = 0; j < 4; j++) {
        ar[j] += v.x * cr[j] - v.y * ci[j];
        ai[j] += v.y * cr[j] + v.x * ci[j];
        float t1 = cr[j] * ca[j] - ci[j] * sa[j];
        ci[j] = cr[j] * sa[j] + ci[j] * ca[j]; cr[j] = t1;
      }
    }
    #pragma unroll
    for (int j = 0; j < 4; j++) {
      int k0 = w * 4 + j;
      spec[reb + (size_t)k0 * WF + l]        = (reE[j] + ar[j]) * scale;
      spec[imb + (size_t)k0 * WF + l]        = (imE[j] + ai[j]) * scale;
      spec[reb + (size_t)(k0 + 64) * WF + l] = (reE[j] - ar[j]) * scale;
      spec[imb + (size_t)(k0 + 64) * WF + l] = (imE[j] - ai[j]) * scale;
    }
    if (w == 0) {
      float a0 = (float)l * (1.f / 64.f);
      float crr = cospif(a0), cii = sinpif(a0) * sgn;
      float rO = 0.f, iO = 0.f;
      for (int i = 0; i < 64; i++) {
        float2 v = tile[i * 65 + 64];
        rO += v.x * crr - v.y * cii; iO += v.y * crr + v.x * cii;
        float t1 = crr * a64c - cii * a64s; cii = crr * a64s + cii * a64c; crr = t1;
      }
      spec[reb + (size_t)l * WF + 64]        = (rE64 + rO) * scale;
      spec[imb + (size_t)l * WF + 64]        = (iE64 + iO) * scale;
      spec[reb + (size_t)(l + 64) * WF + 64] = (rE64 - rO) * scale;
      spec[imb + (size_t)(l + 64) * WF + 64] = (iE64 - iO) * scale;
    }
  }
}

// ---- freq-domain channel-mix gate: yf *= gelu(W yf + b) ----
__global__ void __launch_bounds__(256) freq_gate_k(float* __restrict__ spec,
                                                   const float* __restrict__ P) {
  __shared__ float vs[96 * 65];
  int t = threadIdx.x;
  int blk = blockIdx.x;
  int b = blk / (SPECHW / 64);
  int pp0 = (blk % (SPECHW / 64)) * 64;
  float* sb = spec + (size_t)b * C2 * SPECHW + pp0;
  #pragma unroll
  for (int i = 0; i < 24; i++) {
    int idx = i * 256 + t;
    int c = idx >> 6, p = idx & 63;
    vs[c * 65 + p] = sb[(size_t)c * SPECHW + p];
  }
  __syncthreads();
  int p = t & 63;
  int og = __builtin_amdgcn_readfirstlane(t >> 6);   // wave-uniform 0..3
  const float* Wrow = P + O_FLW + og * 24 * 96;      // uniform base -> s_loads
  float acc[24];
  #pragma unroll
  for (int j = 0; j < 24; j++) acc[j] = 0.f;
  for (int c = 0; c < 96; c++) {
    float vv = vs[c * 65 + p];
    #pragma unroll
    for (int j = 0; j < 24; j++) acc[j] += Wrow[j * 96 + c] * vv;
  }
  #pragma unroll
  for (int j = 0; j < 24; j++) {
    int o = og * 24 + j;
    float g = geluf(acc[j] + P[O_FLB + o]);
    sb[(size_t)o * SPECHW + p] = vs[o * 65 + p] * g;
  }
}

// ---- irfft along W, v2: recurrence + even/odd-k parity ----
__global__ void __launch_bounds__(256) irfft_row_k(const float* __restrict__ spec,
                                                   bf16* __restrict__ out) {
  int t = threadIdx.x;
  int wid = t >> 6, l = t & 63;
  int row = blockIdx.x * 4 + wid;        // in [0, B*C*H)
  int h = row & (H - 1);
  int bc = row >> 7;
  int c = bc % C, b = bc / C;
  __shared__ float2 rim[4][64];
  __shared__ float r64[4];
  size_t rb = ((size_t)(b * C2 + c) * H + h) * WF;
  size_t ioff = (size_t)C * H * WF;
  rim[wid][l] = make_float2(spec[rb + l], spec[rb + ioff + l]);
  if (l == 0) r64[wid] = spec[rb + 64];
  __syncthreads();
  float re0 = rim[wid][0].x;
  float re64 = r64[wid];
  float a = (float)l * (1.f / 64.f);
  float ca = cospif(a), sa = sinpif(a);
  float cr = ca, ci = sa;                // rotation at k=1
  float accE = 0.f, accO = 0.f;          // even-k / odd-k partials (k>=1)
  #pragma unroll 8
  for (int k = 1; k <= 61; k += 2) {
    float2 v = rim[wid][k];
    accO += v.x * cr - v.y * ci;
    float t1 = cr * ca - ci * sa; ci = cr * sa + ci * ca; cr = t1;   // -> k+1
    v = rim[wid][k + 1];
    accE += v.x * cr - v.y * ci;
    t1 = cr * ca - ci * sa; ci = cr * sa + ci * ca; cr = t1;         // -> k+2
  }
  { // k = 63 epilogue (odd)
    float2 v = rim[wid][63];
    accO += v.x * cr - v.y * ci;
  }
  float base = re0 + ((l & 1) ? -re64 : re64);
  float x0 = (base + 2.f * (accE + accO)) * (1.f / 128.f);
  float x1 = (base + 2.f * (accE - accO)) * (1.f / 128.f);
  bf16* ob = out + (size_t)row * W;
  ob[l] = tob(x0);
  ob[l + 64] = tob(x1);
}

// ---- 1x1 conv v2: 64 px/block, 4 waves x 12 outputs, s_load weights ----
// mode 1: input is the external x (flag-dtyped); mode 0: internal bf16
__global__ void __launch_bounds__(256) conv1x1_k(const void* __restrict__ in, bf16* __restrict__ out,
                                                 const float* __restrict__ w,
                                                 const int* flagp, int mode) {
  int bf = mode ? flagp[0] : 1;
  __shared__ float vs[48 * 64];
  int t = threadIdx.x;
  int blk = blockIdx.x;                // B * 256
  int b = blk >> 8;
  int p0 = (blk & 255) << 6;
  int ibase = b * 48 * HW + p0;
  #pragma unroll
  for (int i = 0; i < 12; i++) {
    int idx = i * 256 + t;
    int c = idx >> 6, p = idx & 63;
    vs[idx] = ldx(in, ibase + c * HW + p, bf);
  }
  __syncthreads();
  int p = t & 63;
  int og = __builtin_amdgcn_readfirstlane(t >> 6);   // wave-uniform 0..3
  const float* Wrow = w + og * 12 * 48;              // uniform -> s_loads
  float acc[12];
  #pragma unroll
  for (int j = 0; j < 12; j++) acc[j] = 0.f;
  for (int c = 0; c < 48; c++) {
    float v = vs[c * 64 + p];
    #pragma unroll
    for (int j = 0; j < 12; j++) acc[j] += Wrow[j * 48 + c] * v;
  }
  bf16* op = out + (size_t)b * 48 * HW + p0 + p;
  #pragma unroll
  for (int j = 0; j < 12; j++) op[(size_t)(og * 12 + j) * HW] = tob(acc[j]);
}

// ---- depthwise 3x3 v2: 4 px/thread, vector row loads, zero pad ----
__global__ void dw3x3_k(const bf16* __restrict__ in, bf16* __restrict__ out,
                        const float* __restrict__ w) {
  int idx4 = blockIdx.x * 256 + threadIdx.x;   // pixel-quad index
  int wq = idx4 & 31;                          // W/4 = 32
  int h = (idx4 >> 5) & (H - 1);
  int plane = idx4 >> 12;                      // b*48 + c  (HW/4 = 4096)
  int c = plane % 48;
  const bf16* p = in + (size_t)plane * HW;
  int w0 = wq << 2;
  float acc[4] = {0.f, 0.f, 0.f, 0.f};
  #pragma unroll
  for (int i = 0; i < 3; i++) {
    int hh = h + i - 1;
    if (hh < 0 || hh >= H) continue;
    const bf16* row = p + hh * W + w0;
    ushort4 u = *(const ushort4*)row;          // 8B-aligned (w0 % 4 == 0)
    float v[6];
    v[1] = u2f(u.x); v[2] = u2f(u.y); v[3] = u2f(u.z); v[4] = u2f(u.w);
    v[0] = (w0 > 0) ? ldf(row, -1) : 0.f;
    v[5] = (w0 + 4 < W) ? ldf(row, 4) : 0.f;
    #pragma unroll
    for (int j = 0; j < 3; j++) {
      float wt = w[c * 9 + i * 3 + j];
      #pragma unroll
      for (int q = 0; q < 4; q++) acc[q] += wt * v[q + j];
    }
  }
  ushort4 o;
  o.x = b2u(tob(acc[0])); o.y = b2u(tob(acc[1]));
  o.z = b2u(tob(acc[2])); o.w = b2u(tob(acc[3]));
  *(ushort4*)(out + (size_t)idx4 * 4) = o;
}

// ---- attn gram, split-L partials: grid = 32 bh * NCHUNK blocks ----
__global__ void __launch_bounds__(256) attn_part_k(const bf16* __restrict__ q,
                                                   const bf16* __restrict__ kbuf,
                                                   float* __restrict__ partial) {
  int blk = blockIdx.x;
  int bh = blk >> 6, chunk = blk & (NCHUNK - 1);
  int b = bh >> 2, hd = bh & 3;
  int t = threadIdx.x;
  int l0 = chunk * 256;
  __shared__ float qs[12 * 257], ks[12 * 257];
  const bf16* qb = q + (size_t)(b * 48 + hd * 12) * HW + l0;
  const bf16* kb = kbuf + (size_t)(b * 48 + hd * 12) * HW + l0;
  #pragma unroll
  for (int m = 0; m < 12; m++) {
    qs[m * 257 + t] = ldf(qb, m * HW + t);
    ks[m * 257 + t] = ldf(kb, m * HW + t);
  }
  __syncthreads();
  float acc = 0.f;
  if (t < 144) {
    const float* qr = qs + (t / 12) * 257;
    const float* kr = ks + (t % 12) * 257;
    #pragma unroll 4
    for (int j = 0; j < 256; j++) acc += qr[j] * kr[j];
  } else if (t < 156) {
    const float* qr = qs + (t - 144) * 257;
    #pragma unroll 4
    for (int j = 0; j < 256; j++) acc += qr[j] * qr[j];
  } else if (t < 168) {
    const float* kr = ks + (t - 156) * 257;
    #pragma unroll 4
    for (int j = 0; j < 256; j++) acc += kr[j] * kr[j];
  }
  if (t < 168) partial[(size_t)(chunk * 32 + bh) * 168 + t] = acc;
}

// ---- reduce partials + norms + softmax -> 12x12 attn per bh ----
__global__ void __launch_bounds__(256) attn_fin_k(const float* __restrict__ partial,
                                                  const float* __restrict__ temp,
                                                  float* __restrict__ attn) {
  int bh = blockIdx.x, hd = bh & 3;
  int t = threadIdx.x;
  __shared__ float red[168];
  if (t < 168) {
    float s = 0.f;
    for (int ch = 0; ch < NCHUNK; ch++) s += partial[(size_t)(ch * 32 + bh) * 168 + t];
    red[t] = s;
  }
  __syncthreads();
  if (t < 12) {
    float tm = temp[hd];
    float rq = 1.f / fmaxf(sqrtf(red[144 + t]), 1e-12f);
    float vals[12], mx = -1e30f;
    #pragma unroll
    for (int d = 0; d < 12; d++) {
      float rk = 1.f / fmaxf(sqrtf(red[156 + d]), 1e-12f);
      vals[d] = red[t * 12 + d] * rq * rk * tm;
      mx = fmaxf(mx, vals[d]);
    }
    float s = 0.f;
    #pragma unroll
    for (int d = 0; d < 12; d++) { vals[d] = expf(vals[d] - mx); s += vals[d]; }
    float inv = 1.f / s;
    float* ao = attn + (size_t)(bh * 12 + t) * 12;
    #pragma unroll
    for (int d = 0; d < 12; d++) ao[d] = vals[d] * inv;
  }
}

// ---- out = attn @ v ----
__global__ void attn_apply_k(const float* __restrict__ attn, const bf16* __restrict__ vbuf,
                             bf16* __restrict__ out) {
  int blk = blockIdx.x;
  int bh = blk >> 6, b = bh >> 2, hd = bh & 3;
  int l = ((blk & 63) << 8) + threadIdx.x;
  __shared__ float al[144];
  if (threadIdx.x < 144) al[threadIdx.x] = attn[bh * 144 + threadIdx.x];
  __syncthreads();
  const bf16* vb = vbuf + (size_t)(b * 48 + hd * 12) * HW + l;
  float vv[12];
  #pragma unroll
  for (int d = 0; d < 12; d++) vv[d] = ldf(vb, d * HW);
  bf16* ob = out + (size_t)(b * 48 + hd * 12) * HW + l;
  #pragma unroll
  for (int c = 0; c < 12; c++) {
    float s = 0.f;
    #pragma unroll
    for (int d = 0; d < 12; d++) s += al[c * 12 + d] * vv[d];
    ob[(size_t)c * HW] = tob(s);
  }
}

// ---- final v2: 64 px/block, 4 waves x 12 outputs, s_load weights ----
__global__ void __launch_bounds__(256) conv_final_k(const bf16* __restrict__ ho,
                                                    const bf16* __restrict__ lo,
                                                    const float* __restrict__ P,
                                                    const void* __restrict__ x,
                                                    void* __restrict__ out,
                                                    const int* flagp) {
  int bf = flagp[0];
  __shared__ float vs[96 * 64];
  int t = threadIdx.x;
  int blk = blockIdx.x;                // B * 256
  int b = blk >> 8;
  int p0 = (blk & 255) << 6;
  int pbase = b * 48 * HW + p0;
  #pragma unroll
  for (int i = 0; i < 12; i++) {
    int idx = i * 256 + t;
    int c = idx >> 6, p = idx & 63;
    vs[idx] = ldf(ho, pbase + c * HW + p);
    vs[48 * 64 + idx] = ldf(lo, pbase + c * HW + p);
  }
  __syncthreads();
  int p = t & 63;
  int og = __builtin_amdgcn_readfirstlane(t >> 6);   // wave-uniform 0..3
  const float* Wrow = P + O_FPW + og * 12 * 96;      // uniform -> s_loads
  float acc[12];
  #pragma unroll
  for (int j = 0; j < 12; j++) acc[j] = 0.f;
  for (int c = 0; c < 96; c++) {
    float v = vs[c * 64 + p];
    #pragma unroll
    for (int j = 0; j < 12; j++) acc[j] += Wrow[j * 96 + c] * v;
  }
  #pragma unroll
  for (int j = 0; j < 12; j++) {
    int o = og * 12 + j;
    int oi = pbase + o * HW + p;
    float val = acc[j] + P[O_FPB + o] + ldx(x, oi, bf);
    if (bf) ((bf16*)out)[oi] = tob(val);
    else    ((float*)out)[oi] = val;
  }
}

extern "C" void kernel_launch(void* const* d_in, const int* in_sizes, int n_in,
                              void* d_out, int out_size, void* d_ws, size_t ws_size,
                              hipStream_t stream) {
  const void* x = d_in[0];

  // ws layout (fp32 units): ap@0, wts@512, attnm@2048, flag@7000,
  // params@8192 (ends 47224), partials@49152 (64*32*168 -> ends 393216),
  // bf16 planes @400000
  float* ws    = (float*)d_ws;
  float* ap    = ws;
  float* wts   = ws + 512;
  float* attnm = ws + 2048;
  int*   flagp = (int*)(ws + 7000);
  float* P     = ws + 8192;
  float* parts = ws + 49152;
  bf16* base = (bf16*)(ws + 400000);
  bf16* HF = base;
  bf16* LF = base + (size_t)NCHW;
  bf16* T  = base + (size_t)2 * NCHW;
  bf16* Q  = base + (size_t)3 * NCHW;
  bf16* K  = base + (size_t)4 * NCHW;
  float* spec = (float*)T;

  // ---- dtype detect + param convert ----
  detect_k<<<1, 256, 0, stream>>>(x, flagp);
  ParamTab tab;
  const int offs[25] = {O_FDW, O_BNG, O_BNB, O_BNM, O_BNV,
                        O_FHW1, O_FHB1, O_FHW2, O_FHB2,
                        O_FLW, O_FLB,
                        O_HQW, O_HKVW, O_HQDW, O_HKVDW, O_HPW, O_HT,
                        O_LQW, O_LKVW, O_LQDW, O_LKVDW, O_LPW, O_LT,
                        O_FPW, O_FPB};
  const int cnts[25] = {3456, 72, 72, 72, 72,
                        144, 48, 144, 48,
                        9216, 96,
                        2304, 4608, 432, 864, 2304, 4,
                        2304, 4608, 432, 864, 2304, 4,
                        4608, 48};
  for (int i = 0; i < 25; i++) { tab.src[i] = d_in[i + 1]; tab.off[i] = offs[i]; tab.cnt[i] = cnts[i]; }
  cvt_params_k<<<25, 256, 0, stream>>>(tab, flagp, P);

  // ---- fd ----
  reduce_mean_k<<<B * C, 256, 0, stream>>>(x, ap, flagp);
  fd_weights_k<<<B, 128, 0, stream>>>(ap, P, wts);
  fd_apply_k<<<NCHW / 256, 256, 0, stream>>>(x, wts, LF, Q, flagp);   // low->LF, high->Q
  // ---- fmgm_high ----
  fmgm_high_k<<<NCHW / 256, 256, 0, stream>>>(Q, P, HF);              // hf->HF
  // ---- fmgm_low: rfft2 -> gate -> irfft2 ----
  rfft_row_k<<<B * C * H / 4, 256, 0, stream>>>(LF, spec);
  fft_col_k<<<B * C, 1024, 0, stream>>>(spec, -1.f, 1.f);
  freq_gate_k<<<B * (SPECHW / 64), 256, 0, stream>>>(spec, P);
  fft_col_k<<<B * C, 1024, 0, stream>>>(spec, 1.f, 1.f / 128.f);
  irfft_row_k<<<B * C * H / 4, 256, 0, stream>>>(spec, LF);           // lf->LF
  // ---- fga (high branch: freq = hf in HF) ----
  conv1x1_k<<<B * 256, 256, 0, stream>>>(HF, T, P + O_HQW, flagp, 0);
  dw3x3_k<<<NCHW / 1024, 256, 0, stream>>>(T, Q, P + O_HQDW);         // q->Q (high dead)
  conv1x1_k<<<B * 256, 256, 0, stream>>>(x, T, P + O_HKVW, flagp, 1);
  dw3x3_k<<<NCHW / 1024, 256, 0, stream>>>(T, K, P + O_HKVDW);        // k->K
  conv1x1_k<<<B * 256, 256, 0, stream>>>(x, T, P + O_HKVW + 48 * 48, flagp, 1);
  dw3x3_k<<<NCHW / 1024, 256, 0, stream>>>(T, HF, P + O_HKVDW + 48 * 9); // v->HF (hf dead)
  attn_part_k<<<32 * NCHUNK, 256, 0, stream>>>(Q, K, parts);
  attn_fin_k<<<32, 256, 0, stream>>>(parts, P + O_HT, attnm);
  attn_apply_k<<<B * 4 * 64, 256, 0, stream>>>(attnm, HF, K);         // attnout->K (k dead)
  conv1x1_k<<<B * 256, 256, 0, stream>>>(K, Q, P + O_HPW, flagp, 0);  // ho->Q (q dead)
  // ---- fga (low branch: freq = lf in LF) ----
  conv1x1_k<<<B * 256, 256, 0, stream>>>(LF, T, P + O_LQW, flagp, 0);
  dw3x3_k<<<NCHW / 1024, 256, 0, stream>>>(T, HF, P + O_LQDW);        // q->HF
  conv1x1_k<<<B * 256, 256, 0, stream>>>(x, T, P + O_LKVW, flagp, 1);
  dw3x3_k<<<NCHW / 1024, 256, 0, stream>>>(T, K, P + O_LKVDW);        // k->K
  conv1x1_k<<<B * 256, 256, 0, stream>>>(x, T, P + O_LKVW + 48 * 48, flagp, 1);
  dw3x3_k<<<NCHW / 1024, 256, 0, stream>>>(T, LF, P + O_LKVDW + 48 * 9); // v->LF (lf dead)
  attn_part_k<<<32 * NCHUNK, 256, 0, stream>>>(HF, K, parts);
  attn_fin_k<<<32, 256, 0, stream>>>(parts, P + O_LT, attnm);
  attn_apply_k<<<B * 4 * 64, 256, 0, stream>>>(attnm, LF, K);         // attnout->K
  conv1x1_k<<<B * 256, 256, 0, stream>>>(K, T, P + O_LPW, flagp, 0);  // lo->T
  // ---- final 1x1 + bias + residual ----
  conv_final_k<<<B * 256, 256, 0, stream>>>(Q, T, P, x, d_out, flagp);
}

// Round 11
// 861.731 us; speedup vs baseline: 1.1801x; 1.0518x over previous
//
#include <hip/hip_runtime.h>
#include <hip/hip_bf16.h>
#include <math.h>

using bf16 = __hip_bfloat16;
#define DI __device__ __forceinline__

namespace {
constexpr int B = 8, C = 48, H = 128, W = 128;
constexpr int HW = H * W;                 // 16384
constexpr int NCHW = B * C * HW;          // 6,291,456
constexpr int C2 = 96;
constexpr int WF = 65;                    // rfft width
constexpr int SPECHW = H * WF;            // 8320 (divisible by 64)
constexpr int SPECN = B * C2 * SPECHW;    // 6,389,760 floats
// spec (fp32) overlays the T+Q+K bf16 region = 3*NCHW bf16 slots
static_assert((size_t)SPECN * 4 <= (size_t)3 * NCHW * 2, "spec must fit in T+Q+K overlay");
static_assert(SPECHW % 64 == 0, "freq_gate 64-pixel blocks must not straddle batches");

// fp32 param header offsets (in floats), base = ws + 8192
constexpr int O_FDW = 0,    O_BNG = 3456, O_BNB = 3528, O_BNM = 3600, O_BNV = 3672;
constexpr int O_FHW1 = 3744, O_FHB1 = 3888, O_FHW2 = 3936, O_FHB2 = 3984;
constexpr int O_FLW = 4032,  O_FLB = 13248;
constexpr int O_HQW = 13344, O_HKVW = 15648, O_HQDW = 20256, O_HKVDW = 20688, O_HPW = 21552, O_HT = 23856;
constexpr int O_LQW = 23860, O_LKVW = 26164, O_LQDW = 30772, O_LKVDW = 31204, O_LPW = 32068, O_LT = 34372;
constexpr int O_FPW = 34376, O_FPB = 38984;  // end 39032

constexpr int NCHUNK = 64;                // L split for attn gram
}

DI float ldf(const float* p, int i) { return p[i]; }
DI float ldf(const bf16* p, int i) { return __bfloat162float(p[i]); }
DI bf16 tob(float x) { return __float2bfloat16(x); }
DI unsigned short b2u(bf16 v) { union { bf16 b; unsigned short u; } x; x.b = v; return x.u; }
DI float u2f(unsigned short u) { return __uint_as_float((unsigned)u << 16); }
DI float ldx(const void* p, int i, int bf) {
  return bf ? __bfloat162float(((const bf16*)p)[i]) : ((const float*)p)[i];
}
DI float geluf(float x) { return 0.5f * x * (1.f + erff(x * 0.70710678118654752f)); }
DI int refl(int i, int n) { return i < 0 ? -i : (i >= n ? 2 * n - 2 - i : i); }

// ---- dtype detector: bf16 data -> even u16 slots have sane exponents ----
__global__ void detect_k(const void* x, int* flagp) {
  const unsigned short* u = (const unsigned short*)x;
  int t = threadIdx.x;
  int good = 0;
  for (int i = t; i < 1024; i += 256) {
    unsigned short v = u[2 * i];
    int e = (v >> 7) & 0xFF;
    if (e >= 100 && e <= 140) good++;
  }
  __shared__ int cnt;
  if (t == 0) cnt = 0;
  __syncthreads();
  atomicAdd(&cnt, good);
  __syncthreads();
  if (t == 0) flagp[0] = (cnt > 512) ? 1 : 0;
}

// ---- convert all params to fp32 header ----
struct ParamTab { const void* src[25]; int off[25]; int cnt[25]; };
__global__ void cvt_params_k(ParamTab tab, const int* flagp, float* dst) {
  int bf = flagp[0];
  int b = blockIdx.x;
  const void* s = tab.src[b];
  float* d = dst + tab.off[b];
  int n = tab.cnt[b];
  for (int i = threadIdx.x; i < n; i += 256) d[i] = ldx(s, i, bf);
}

// ---- fd: channel means ----
__global__ void reduce_mean_k(const void* __restrict__ x, float* __restrict__ ap,
                              const int* flagp) {
  int bf = flagp[0];
  int bc = blockIdx.x;
  int base = bc * HW;
  float s = 0.f;
  for (int i = threadIdx.x; i < HW; i += 256) s += ldx(x, base + i, bf);
  #pragma unroll
  for (int o = 32; o > 0; o >>= 1) s += __shfl_down(s, o);
  __shared__ float r[4];
  if ((threadIdx.x & 63) == 0) r[threadIdx.x >> 6] = s;
  __syncthreads();
  if (threadIdx.x == 0) ap[bc] = (r[0] + r[1] + r[2] + r[3]) * (1.f / HW);
}

// ---- fd: 72-wide linear + BN + per-group softmax over 9 ----
__global__ void fd_weights_k(const float* __restrict__ ap, const float* __restrict__ P,
                             float* __restrict__ wts) {
  int n = blockIdx.x, t = threadIdx.x;
  __shared__ float vals[72], es[72];
  if (t < 72) {
    float acc = 0.f;
    for (int c = 0; c < C; c++) acc += P[O_FDW + t * C + c] * ap[n * C + c];
    acc = (acc - P[O_BNM + t]) * rsqrtf(P[O_BNV + t] + 1e-5f);
    vals[t] = acc * P[O_BNG + t] + P[O_BNB + t];
  }
  __syncthreads();
  if (t < 72) {
    int base = (t / 9) * 9;
    float mx = -1e30f;
    for (int k = 0; k < 9; k++) mx = fmaxf(mx, vals[base + k]);
    es[t] = expf(vals[t] - mx);
  }
  __syncthreads();
  if (t < 72) {
    int base = (t / 9) * 9;
    float s = 0.f;
    for (int k = 0; k < 9; k++) s += es[base + k];
    wts[n * 72 + t] = es[t] / s;
  }
}

// ---- fd: involution low-pass (reflect pad), low + high ----
__global__ void fd_apply_k(const void* __restrict__ x, const float* __restrict__ wts,
                           bf16* __restrict__ low, bf16* __restrict__ high,
                           const int* flagp) {
  int bf = flagp[0];
  int idx = blockIdx.x * 256 + threadIdx.x;
  int w = idx & (W - 1);
  int h = (idx >> 7) & (H - 1);
  int c = (idx / HW) % C;
  int b = idx / (C * HW);
  const float* wt = wts + b * 72 + (c / 6) * 9;
  int xbase = (b * C + c) * HW;
  float acc = 0.f, ctr = 0.f;
  #pragma unroll
  for (int i = 0; i < 3; i++) {
    int hh = refl(h + i - 1, H);
    #pragma unroll
    for (int j = 0; j < 3; j++) {
      int ww = refl(w + j - 1, W);
      float v = ldx(x, xbase + hh * W + ww, bf);
      if (i == 1 && j == 1) ctr = v;
      acc += wt[i * 3 + j] * v;
    }
  }
  low[idx] = tob(acc);
  high[idx] = tob(ctr - acc);
}

// ---- fmgm_high: fused (1x3)->(3x1) dwconv (zero pad, biases) -> gelu * x ----
__global__ void fmgm_high_k(const bf16* __restrict__ hi, const float* __restrict__ P,
                            bf16* __restrict__ out) {
  int idx = blockIdx.x * 256 + threadIdx.x;
  int w = idx & (W - 1);
  int h = (idx >> 7) & (H - 1);
  int c = (idx / HW) % C;
  const bf16* p = hi + (idx - (h * W + w));
  float k1[3], k2[3];
  #pragma unroll
  for (int j = 0; j < 3; j++) { k1[j] = P[O_FHW1 + c * 3 + j]; k2[j] = P[O_FHW2 + c * 3 + j]; }
  float bb1 = P[O_FHB1 + c];
  float acc = P[O_FHB2 + c];
  #pragma unroll
  for (int i = 0; i < 3; i++) {
    int hh = h + i - 1;
    if (hh < 0 || hh >= H) continue;
    float y1 = bb1;
    #pragma unroll
    for (int j = 0; j < 3; j++) {
      int ww = w + j - 1;
      if (ww >= 0 && ww < W) y1 += k1[j] * ldf(p, hh * W + ww);
    }
    acc += k2[i] * y1;
  }
  out[idx] = tob(geluf(acc) * ldf(p, h * W + w));
}

// ---- rfft along W, v2: trig recurrence, 4 rows/block, 1 wave/row ----
__global__ void __launch_bounds__(256) rfft_row_k(const bf16* __restrict__ low,
                                                  float* __restrict__ spec) {
  int t = threadIdx.x;
  int wid = t >> 6, l = t & 63;
  int row = blockIdx.x * 4 + wid;        // in [0, B*C*H)
  int h = row & (H - 1);
  int bc = row >> 7;
  int c = bc % C, b = bc / C;
  __shared__ float2 xs[4][64];
  const unsigned* xr = (const unsigned*)(low + (size_t)row * W);
  unsigned v2 = xr[l];                   // two bf16: elems 2l, 2l+1
  xs[wid][l] = make_float2(__uint_as_float(v2 << 16),
                           __uint_as_float(v2 & 0xFFFF0000u));
  __syncthreads();
  float a = (float)l * (1.f / 64.f);
  float ca = cospif(a), sa = sinpif(a);
  float cr = 1.f, ci = 0.f;
  float re = 0.f, im = 0.f, se = 0.f, so = 0.f;
  #pragma unroll 8
  for (int i = 0; i < 64; i++) {
    float2 v = xs[wid][i];
    re += v.x * cr; im -= v.x * ci;      // n = 2i
    se += v.x; so += v.y;
    float t1 = cr * ca - ci * sa; ci = cr * sa + ci * ca; cr = t1;  // -> n=2i+1
    re += v.y * cr; im -= v.y * ci;
    t1 = cr * ca - ci * sa; ci = cr * sa + ci * ca; cr = t1;        // -> n=2i+2
  }
  size_t o = ((size_t)(b * C2 + c) * H + h) * WF + l;
  size_t ioff = (size_t)C * H * WF;
  spec[o] = re;
  spec[o + ioff] = im;
  if (l == 0) {                          // k = 64 (Nyquist): im exactly 0
    spec[o + 64] = se - so;
    spec[o + 64 + ioff] = 0.f;
  }
}

// ---- complex DFT along H, v5: kx-split tiles (disjoint in-place), 1 barrier ----
// grid = B*C*2; half 0 owns kx[0,32), half 1 owns kx[32,65). 512 thr = 8 waves.
// lane: c = l&31 (kx = kx0+c), sub = l>>5; k0 = w*8 + sub*4 + j, j<4.
// E/O row-parity accumulators in one 128-step twiddle chain -> k0 and k0+64.
__global__ void __launch_bounds__(512) fft_col_k(float* __restrict__ spec,
                                                 float sgn, float scale) {
  __shared__ float2 tile[128 * 34];      // 34.8 KB, width padded to 34
  int t = threadIdx.x;
  int half = blockIdx.x & 1;
  int bc = blockIdx.x >> 1;
  int cc = bc % C, b = bc / C;
  size_t reb = ((size_t)(b * C2 + cc) * H) * WF;
  size_t imb = reb + (size_t)C * H * WF;
  if (half == 0) {
    #pragma unroll
    for (int i = 0; i < 8; i++) {
      int idx = i * 512 + t;             // 4096 = 128*32
      int r = idx >> 5, c = idx & 31;
      tile[r * 34 + c] = make_float2(spec[reb + r * WF + c], spec[imb + r * WF + c]);
    }
  } else {
    #pragma unroll
    for (int i = 0; i < 9; i++) {
      int idx = i * 512 + t;             // 4224 >= 128*33
      if (idx < 128 * 33) {
        int r = idx / 33, c = idx - r * 33;
        tile[r * 34 + c] = make_float2(spec[reb + r * WF + 32 + c],
                                       spec[imb + r * WF + 32 + c]);
      }
    }
  }
  __syncthreads();
  int w = t >> 6, l = t & 63;
  int c = l & 31, sub = l >> 5;
  int kx = (half ? 32 : 0) + c;
  int k0b = w * 8 + sub * 4;
  float ca[4], sa[4], cr[4], ci[4];
  float Er[4] = {0,0,0,0}, Ei[4] = {0,0,0,0}, Or[4] = {0,0,0,0}, Oi[4] = {0,0,0,0};
  #pragma unroll
  for (int j = 0; j < 4; j++) {
    float a = (float)(k0b + j) * (1.f / 64.f);   // step per n += 1
    ca[j] = cospif(a); sa[j] = sinpif(a) * sgn;
    cr[j] = 1.f; ci[j] = 0.f;
  }
  #pragma unroll 4
  for (int n = 0; n < 128; n += 2) {
    float2 v = tile[n * 34 + c];
    #pragma unroll
    for (int j = 0; j < 4; j++) {
      Er[j] += v.x * cr[j] - v.y * ci[j];
      Ei[j] += v.y * cr[j] + v.x * ci[j];
      float t1 = cr[j] * ca[j] - ci[j] * sa[j];
      ci[j] = cr[j] * sa[j] + ci[j] * ca[j]; cr[j] = t1;
    }
    v = tile[(n + 1) * 34 + c];
    #pragma unroll
    for (int j = 0; j < 4; j++) {
      Or[j] += v.x * cr[j] - v.y * ci[j];
      Oi[j] += v.y * cr[j] + v.x * ci[j];
      float t1 = cr[j] * ca[j] - ci[j] * sa[j];
      ci[j] = cr[j] * sa[j] + ci[j] * ca[j]; cr[j] = t1;
    }
  }
  #pragma unroll
  for (int j = 0; j < 4; j++) {
    int k0 = k0b + j;
    spec[reb + (size_t)k0 * WF + kx]        = (Er[j] + Or[j]) * scale;
    spec[imb + (size_t)k0 * WF + kx]        = (Ei[j] + Oi[j]) * scale;
    spec[reb + (size_t)(k0 + 64) * WF + kx] = (Er[j] - Or[j]) * scale;
    spec[imb + (size_t)(k0 + 64) * WF + kx] = (Ei[j] - Oi[j]) * scale;
  }
  if (half == 1 && w == 0) {             // kx = 64 column: lane l = k0, broadcast LDS
    float a = (float)l * (1.f / 64.f);
    float cA = cospif(a), sA = sinpif(a) * sgn;
    float rr = 1.f, ii = 0.f, eR = 0.f, eI = 0.f, oR = 0.f, oI = 0.f;
    for (int n = 0; n < 128; n += 2) {
      float2 v = tile[n * 34 + 32];
      eR += v.x * rr - v.y * ii; eI += v.y * rr + v.x * ii;
      float t1 = rr * cA - ii * sA; ii = rr * sA + ii * cA; rr = t1;
      v = tile[(n + 1) * 34 + 32];
      oR += v.x * rr - v.y * ii; oI += v.y * rr + v.x * ii;
      t1 = rr * cA - ii * sA; ii = rr * sA + ii * cA; rr = t1;
    }
    spec[reb + (size_t)l * WF + 64]        = (eR + oR) * scale;
    spec[imb + (size_t)l * WF + 64]        = (eI + oI) * scale;
    spec[reb + (size_t)(l + 64) * WF + 64] = (eR - oR) * scale;
    spec[imb + (size_t)(l + 64) * WF + 64] = (eI - oI) * scale;
  }
}

// ---- freq-domain channel-mix gate: yf *= gelu(W yf + b) ----
__global__ void __launch_bounds__(256) freq_gate_k(float* __restrict__ spec,
                                                   const float* __restrict__ P) {
  __shared__ float vs[96 * 65];
  int t = threadIdx.x;
  int blk = blockIdx.x;
  int b = blk / (SPECHW / 64);
  int pp0 = (blk % (SPECHW / 64)) * 64;
  float* sb = spec + (size_t)b * C2 * SPECHW + pp0;
  #pragma unroll
  for (int i = 0; i < 24; i++) {
    int idx = i * 256 + t;
    int c = idx >> 6, p = idx & 63;
    vs[c * 65 + p] = sb[(size_t)c * SPECHW + p];
  }
  __syncthreads();
  int p = t & 63;
  int og = __builtin_amdgcn_readfirstlane(t >> 6);   // wave-uniform 0..3
  const float* Wrow = P + O_FLW + og * 24 * 96;      // uniform base -> s_loads
  float acc[24];
  #pragma unroll
  for (int j = 0; j < 24; j++) acc[j] = 0.f;
  for (int c = 0; c < 96; c++) {
    float vv = vs[c * 65 + p];
    #pragma unroll
    for (int j = 0; j < 24; j++) acc[j] += Wrow[j * 96 + c] * vv;
  }
  #pragma unroll
  for (int j = 0; j < 24; j++) {
    int o = og * 24 + j;
    float g = geluf(acc[j] + P[O_FLB + o]);
    sb[(size_t)o * SPECHW + p] = vs[o * 65 + p] * g;
  }
}

// ---- irfft along W, v2: recurrence + even/odd-k parity ----
__global__ void __launch_bounds__(256) irfft_row_k(const float* __restrict__ spec,
                                                   bf16* __restrict__ out) {
  int t = threadIdx.x;
  int wid = t >> 6, l = t & 63;
  int row = blockIdx.x * 4 + wid;        // in [0, B*C*H)
  int h = row & (H - 1);
  int bc = row >> 7;
  int c = bc % C, b = bc / C;
  __shared__ float2 rim[4][64];
  __shared__ float r64[4];
  size_t rb = ((size_t)(b * C2 + c) * H + h) * WF;
  size_t ioff = (size_t)C * H * WF;
  rim[wid][l] = make_float2(spec[rb + l], spec[rb + ioff + l]);
  if (l == 0) r64[wid] = spec[rb + 64];
  __syncthreads();
  float re0 = rim[wid][0].x;
  float re64 = r64[wid];
  float a = (float)l * (1.f / 64.f);
  float ca = cospif(a), sa = sinpif(a);
  float cr = ca, ci = sa;                // rotation at k=1
  float accE = 0.f, accO = 0.f;          // even-k / odd-k partials (k>=1)
  #pragma unroll 8
  for (int k = 1; k <= 61; k += 2) {
    float2 v = rim[wid][k];
    accO += v.x * cr - v.y * ci;
    float t1 = cr * ca - ci * sa; ci = cr * sa + ci * ca; cr = t1;   // -> k+1
    v = rim[wid][k + 1];
    accE += v.x * cr - v.y * ci;
    t1 = cr * ca - ci * sa; ci = cr * sa + ci * ca; cr = t1;         // -> k+2
  }
  { // k = 63 epilogue (odd)
    float2 v = rim[wid][63];
    accO += v.x * cr - v.y * ci;
  }
  float base = re0 + ((l & 1) ? -re64 : re64);
  float x0 = (base + 2.f * (accE + accO)) * (1.f / 128.f);
  float x1 = (base + 2.f * (accE - accO)) * (1.f / 128.f);
  bf16* ob = out + (size_t)row * W;
  ob[l] = tob(x0);
  ob[l + 64] = tob(x1);
}

// ---- 1x1 conv v2: 64 px/block, 4 waves x 12 outputs, s_load weights ----
// mode 1: input is the external x (flag-dtyped); mode 0: internal bf16
__global__ void __launch_bounds__(256) conv1x1_k(const void* __restrict__ in, bf16* __restrict__ out,
                                                 const float* __restrict__ w,
                                                 const int* flagp, int mode) {
  int bf = mode ? flagp[0] : 1;
  __shared__ float vs[48 * 64];
  int t = threadIdx.x;
  int blk = blockIdx.x;                // B * 256
  int b = blk >> 8;
  int p0 = (blk & 255) << 6;
  int ibase = b * 48 * HW + p0;
  #pragma unroll
  for (int i = 0; i < 12; i++) {
    int idx = i * 256 + t;
    int c = idx >> 6, p = idx & 63;
    vs[idx] = ldx(in, ibase + c * HW + p, bf);
  }
  __syncthreads();
  int p = t & 63;
  int og = __builtin_amdgcn_readfirstlane(t >> 6);   // wave-uniform 0..3
  const float* Wrow = w + og * 12 * 48;              // uniform -> s_loads
  float acc[12];
  #pragma unroll
  for (int j = 0; j < 12; j++) acc[j] = 0.f;
  for (int c = 0; c < 48; c++) {
    float v = vs[c * 64 + p];
    #pragma unroll
    for (int j = 0; j < 12; j++) acc[j] += Wrow[j * 48 + c] * v;
  }
  bf16* op = out + (size_t)b * 48 * HW + p0 + p;
  #pragma unroll
  for (int j = 0; j < 12; j++) op[(size_t)(og * 12 + j) * HW] = tob(acc[j]);
}

// ---- depthwise 3x3 v2: 4 px/thread, vector row loads, zero pad ----
__global__ void dw3x3_k(const bf16* __restrict__ in, bf16* __restrict__ out,
                        const float* __restrict__ w) {
  int idx4 = blockIdx.x * 256 + threadIdx.x;   // pixel-quad index
  int wq = idx4 & 31;                          // W/4 = 32
  int h = (idx4 >> 5) & (H - 1);
  int plane = idx4 >> 12;                      // b*48 + c  (HW/4 = 4096)
  int c = plane % 48;
  const bf16* p = in + (size_t)plane * HW;
  int w0 = wq << 2;
  float acc[4] = {0.f, 0.f, 0.f, 0.f};
  #pragma unroll
  for (int i = 0; i < 3; i++) {
    int hh = h + i - 1;
    if (hh < 0 || hh >= H) continue;
    const bf16* row = p + hh * W + w0;
    ushort4 u = *(const ushort4*)row;          // 8B-aligned (w0 % 4 == 0)
    float v[6];
    v[1] = u2f(u.x); v[2] = u2f(u.y); v[3] = u2f(u.z); v[4] = u2f(u.w);
    v[0] = (w0 > 0) ? ldf(row, -1) : 0.f;
    v[5] = (w0 + 4 < W) ? ldf(row, 4) : 0.f;
    #pragma unroll
    for (int j = 0; j < 3; j++) {
      float wt = w[c * 9 + i * 3 + j];
      #pragma unroll
      for (int q = 0; q < 4; q++) acc[q] += wt * v[q + j];
    }
  }
  ushort4 o;
  o.x = b2u(tob(acc[0])); o.y = b2u(tob(acc[1]));
  o.z = b2u(tob(acc[2])); o.w = b2u(tob(acc[3]));
  *(ushort4*)(out + (size_t)idx4 * 4) = o;
}

// ---- attn gram, split-L partials: grid = 32 bh * NCHUNK blocks ----
__global__ void __launch_bounds__(256) attn_part_k(const bf16* __restrict__ q,
                                                   const bf16* __restrict__ kbuf,
                                                   float* __restrict__ partial) {
  int blk = blockIdx.x;
  int bh = blk >> 6, chunk = blk & (NCHUNK - 1);
  int b = bh >> 2, hd = bh & 3;
  int t = threadIdx.x;
  int l0 = chunk * 256;
  __shared__ float qs[12 * 257], ks[12 * 257];
  const bf16* qb = q + (size_t)(b * 48 + hd * 12) * HW + l0;
  const bf16* kb = kbuf + (size_t)(b * 48 + hd * 12) * HW + l0;
  #pragma unroll
  for (int m = 0; m < 12; m++) {
    qs[m * 257 + t] = ldf(qb, m * HW + t);
    ks[m * 257 + t] = ldf(kb, m * HW + t);
  }
  __syncthreads();
  float acc = 0.f;
  if (t < 144) {
    const float* qr = qs + (t / 12) * 257;
    const float* kr = ks + (t % 12) * 257;
    #pragma unroll 4
    for (int j = 0; j < 256; j++) acc += qr[j] * kr[j];
  } else if (t < 156) {
    const float* qr = qs + (t - 144) * 257;
    #pragma unroll 4
    for (int j = 0; j < 256; j++) acc += qr[j] * qr[j];
  } else if (t < 168) {
    const float* kr = ks + (t - 156) * 257;
    #pragma unroll 4
    for (int j = 0; j < 256; j++) acc += kr[j] * kr[j];
  }
  if (t < 168) partial[(size_t)(chunk * 32 + bh) * 168 + t] = acc;
}

// ---- reduce partials + norms + softmax -> 12x12 attn per bh ----
__global__ void __launch_bounds__(256) attn_fin_k(const float* __restrict__ partial,
                                                  const float* __restrict__ temp,
                                                  float* __restrict__ attn) {
  int bh = blockIdx.x, hd = bh & 3;
  int t = threadIdx.x;
  __shared__ float red[168];
  if (t < 168) {
    float s = 0.f;
    for (int ch = 0; ch < NCHUNK; ch++) s += partial[(size_t)(ch * 32 + bh) * 168 + t];
    red[t] = s;
  }
  __syncthreads();
  if (t < 12) {
    float tm = temp[hd];
    float rq = 1.f / fmaxf(sqrtf(red[144 + t]), 1e-12f);
    float vals[12], mx = -1e30f;
    #pragma unroll
    for (int d = 0; d < 12; d++) {
      float rk = 1.f / fmaxf(sqrtf(red[156 + d]), 1e-12f);
      vals[d] = red[t * 12 + d] * rq * rk * tm;
      mx = fmaxf(mx, vals[d]);
    }
    float s = 0.f;
    #pragma unroll
    for (int d = 0; d < 12; d++) { vals[d] = expf(vals[d] - mx); s += vals[d]; }
    float inv = 1.f / s;
    float* ao = attn + (size_t)(bh * 12 + t) * 12;
    #pragma unroll
    for (int d = 0; d < 12; d++) ao[d] = vals[d] * inv;
  }
}

// ---- out = attn @ v ----
__global__ void attn_apply_k(const float* __restrict__ attn, const bf16* __restrict__ vbuf,
                             bf16* __restrict__ out) {
  int blk = blockIdx.x;
  int bh = blk >> 6, b = bh >> 2, hd = bh & 3;
  int l = ((blk & 63) << 8) + threadIdx.x;
  __shared__ float al[144];
  if (threadIdx.x < 144) al[threadIdx.x] = attn[bh * 144 + threadIdx.x];
  __syncthreads();
  const bf16* vb = vbuf + (size_t)(b * 48 + hd * 12) * HW + l;
  float vv[12];
  #pragma unroll
  for (int d = 0; d < 12; d++) vv[d] = ldf(vb, d * HW);
  bf16* ob = out + (size_t)(b * 48 + hd * 12) * HW + l;
  #pragma unroll
  for (int c = 0; c < 12; c++) {
    float s = 0.f;
    #pragma unroll
    for (int d = 0; d < 12; d++) s += al[c * 12 + d] * vv[d];
    ob[(size_t)c * HW] = tob(s);
  }
}

// ---- final v2: 64 px/block, 4 waves x 12 outputs, s_load weights ----
__global__ void __launch_bounds__(256) conv_final_k(const bf16* __restrict__ ho,
                                                    const bf16* __restrict__ lo,
                                                    const float* __restrict__ P,
                                                    const void* __restrict__ x,
                                                    void* __restrict__ out,
                                                    const int* flagp) {
  int bf = flagp[0];
  __shared__ float vs[96 * 64];
  int t = threadIdx.x;
  int blk = blockIdx.x;                // B * 256
  int b = blk >> 8;
  int p0 = (blk & 255) << 6;
  int pbase = b * 48 * HW + p0;
  #pragma unroll
  for (int i = 0; i < 12; i++) {
    int idx = i * 256 + t;
    int c = idx >> 6, p = idx & 63;
    vs[idx] = ldf(ho, pbase + c * HW + p);
    vs[48 * 64 + idx] = ldf(lo, pbase + c * HW + p);
  }
  __syncthreads();
  int p = t & 63;
  int og = __builtin_amdgcn_readfirstlane(t >> 6);   // wave-uniform 0..3
  const float* Wrow = P + O_FPW + og * 12 * 96;      // uniform -> s_loads
  float acc[12];
  #pragma unroll
  for (int j = 0; j < 12; j++) acc[j] = 0.f;
  for (int c = 0; c < 96; c++) {
    float v = vs[c * 64 + p];
    #pragma unroll
    for (int j = 0; j < 12; j++) acc[j] += Wrow[j * 96 + c] * v;
  }
  #pragma unroll
  for (int j = 0; j < 12; j++) {
    int o = og * 12 + j;
    int oi = pbase + o * HW + p;
    float val = acc[j] + P[O_FPB + o] + ldx(x, oi, bf);
    if (bf) ((bf16*)out)[oi] = tob(val);
    else    ((float*)out)[oi] = val;
  }
}

extern "C" void kernel_launch(void* const* d_in, const int* in_sizes, int n_in,
                              void* d_out, int out_size, void* d_ws, size_t ws_size,
                              hipStream_t stream) {
  const void* x = d_in[0];

  // ws layout (fp32 units): ap@0, wts@512, attnm@2048, flag@7000,
  // params@8192 (ends 47224), partials@49152 (64*32*168 -> ends 393216),
  // bf16 planes @400000
  float* ws    = (float*)d_ws;
  float* ap    = ws;
  float* wts   = ws + 512;
  float* attnm = ws + 2048;
  int*   flagp = (int*)(ws + 7000);
  float* P     = ws + 8192;
  float* parts = ws + 49152;
  bf16* base = (bf16*)(ws + 400000);
  bf16* HF = base;
  bf16* LF = base + (size_t)NCHW;
  bf16* T  = base + (size_t)2 * NCHW;
  bf16* Q  = base + (size_t)3 * NCHW;
  bf16* K  = base + (size_t)4 * NCHW;
  float* spec = (float*)T;

  // ---- dtype detect + param convert ----
  detect_k<<<1, 256, 0, stream>>>(x, flagp);
  ParamTab tab;
  const int offs[25] = {O_FDW, O_BNG, O_BNB, O_BNM, O_BNV,
                        O_FHW1, O_FHB1, O_FHW2, O_FHB2,
                        O_FLW, O_FLB,
                        O_HQW, O_HKVW, O_HQDW, O_HKVDW, O_HPW, O_HT,
                        O_LQW, O_LKVW, O_LQDW, O_LKVDW, O_LPW, O_LT,
                        O_FPW, O_FPB};
  const int cnts[25] = {3456, 72, 72, 72, 72,
                        144, 48, 144, 48,
                        9216, 96,
                        2304, 4608, 432, 864, 2304, 4,
                        2304, 4608, 432, 864, 2304, 4,
                        4608, 48};
  for (int i = 0; i < 25; i++) { tab.src[i] = d_in[i + 1]; tab.off[i] = offs[i]; tab.cnt[i] = cnts[i]; }
  cvt_params_k<<<25, 256, 0, stream>>>(tab, flagp, P);

  // ---- fd ----
  reduce_mean_k<<<B * C, 256, 0, stream>>>(x, ap, flagp);
  fd_weights_k<<<B, 128, 0, stream>>>(ap, P, wts);
  fd_apply_k<<<NCHW / 256, 256, 0, stream>>>(x, wts, LF, Q, flagp);   // low->LF, high->Q
  // ---- fmgm_high ----
  fmgm_high_k<<<NCHW / 256, 256, 0, stream>>>(Q, P, HF);              // hf->HF
  // ---- fmgm_low: rfft2 -> gate -> irfft2 ----
  rfft_row_k<<<B * C * H / 4, 256, 0, stream>>>(LF, spec);
  fft_col_k<<<B * C * 2, 512, 0, stream>>>(spec, -1.f, 1.f);
  freq_gate_k<<<B * (SPECHW / 64), 256, 0, stream>>>(spec, P);
  fft_col_k<<<B * C * 2, 512, 0, stream>>>(spec, 1.f, 1.f / 128.f);
  irfft_row_k<<<B * C * H / 4, 256, 0, stream>>>(spec, LF);           // lf->LF
  // ---- fga (high branch: freq = hf in HF) ----
  conv1x1_k<<<B * 256, 256, 0, stream>>>(HF, T, P + O_HQW, flagp, 0);
  dw3x3_k<<<NCHW / 1024, 256, 0, stream>>>(T, Q, P + O_HQDW);         // q->Q (high dead)
  conv1x1_k<<<B * 256, 256, 0, stream>>>(x, T, P + O_HKVW, flagp, 1);
  dw3x3_k<<<NCHW / 1024, 256, 0, stream>>>(T, K, P + O_HKVDW);        // k->K
  conv1x1_k<<<B * 256, 256, 0, stream>>>(x, T, P + O_HKVW + 48 * 48, flagp, 1);
  dw3x3_k<<<NCHW / 1024, 256, 0, stream>>>(T, HF, P + O_HKVDW + 48 * 9); // v->HF (hf dead)
  attn_part_k<<<32 * NCHUNK, 256, 0, stream>>>(Q, K, parts);
  attn_fin_k<<<32, 256, 0, stream>>>(parts, P + O_HT, attnm);
  attn_apply_k<<<B * 4 * 64, 256, 0, stream>>>(attnm, HF, K);         // attnout->K (k dead)
  conv1x1_k<<<B * 256, 256, 0, stream>>>(K, Q, P + O_HPW, flagp, 0);  // ho->Q (q dead)
  // ---- fga (low branch: freq = lf in LF) ----
  conv1x1_k<<<B * 256, 256, 0, stream>>>(LF, T, P + O_LQW, flagp, 0);
  dw3x3_k<<<NCHW / 1024, 256, 0, stream>>>(T, HF, P + O_LQDW);        // q->HF
  conv1x1_k<<<B * 256, 256, 0, stream>>>(x, T, P + O_LKVW, flagp, 1);
  dw3x3_k<<<NCHW / 1024, 256, 0, stream>>>(T, K, P + O_LKVDW);        // k->K
  conv1x1_k<<<B * 256, 256, 0, stream>>>(x, T, P + O_LKVW + 48 * 48, flagp, 1);
  dw3x3_k<<<NCHW / 1024, 256, 0, stream>>>(T, LF, P + O_LKVDW + 48 * 9); // v->LF (lf dead)
  attn_part_k<<<32 * NCHUNK, 256, 0, stream>>>(HF, K, parts);
  attn_fin_k<<<32, 256, 0, stream>>>(parts, P + O_LT, attnm);
  attn_apply_k<<<B * 4 * 64, 256, 0, stream>>>(attnm, LF, K);         // attnout->K
  conv1x1_k<<<B * 256, 256, 0, stream>>>(K, T, P + O_LPW, flagp, 0);  // lo->T
  // ---- final 1x1 + bias + residual ----
  conv_final_k<<<B * 256, 256, 0, stream>>>(Q, T, P, x, d_out, flagp);
}